// Round 3
// baseline (27090.268 us; speedup 1.0000x reference)
//
#include <hip/hip_runtime.h>
#include <stdint.h>
#include <math.h>

typedef unsigned short u16;
typedef short s16x8 __attribute__((ext_vector_type(8)));
typedef __bf16 bv8 __attribute__((ext_vector_type(8)));
typedef float f32x4 __attribute__((ext_vector_type(4)));

#define DEV static __device__ __forceinline__

DEV float b2f(u16 x){ union{unsigned u; float f;} v; v.u=((unsigned)x)<<16; return v.f; }
DEV u16 f2b(float f){ union{float f; unsigned u;} v; v.f=f; unsigned u=v.u; u += 0x7fff + ((u>>16)&1u); return (u16)(u>>16); }
DEV float sigm(float x){ return 1.f/(1.f+expf(-x)); }
DEV f32x4 mfma16(bv8 a, bv8 b, f32x4 c){ return __builtin_amdgcn_mfma_f32_16x16x32_bf16(a,b,c,0,0,0); }
DEV bv8 ldf(const u16* p){ return __builtin_bit_cast(bv8, *(const s16x8*)p); }

// group barrier: monotonic counter, co-resident blocks only (cooperative launch)
DEV void gbar(unsigned* cnt, unsigned target){
  __syncthreads();
  if (threadIdx.x==0){
    __threadfence();
    __hip_atomic_fetch_add(cnt, 1u, __ATOMIC_RELEASE, __HIP_MEMORY_SCOPE_AGENT);
    while (__hip_atomic_load(cnt, __ATOMIC_ACQUIRE, __HIP_MEMORY_SCOPE_AGENT) < target)
      __builtin_amdgcn_s_sleep(2);
  }
  __syncthreads();
  __threadfence();
}

// ---------------- weight f32 -> bf16 conversion ----------------
struct CvtJobs { const float* s[14]; u16* d[14]; int start[14]; };

__global__ __launch_bounds__(256) void cvt_w(CvtJobs J){
  int blk = blockIdx.x, tid = threadIdx.x;
  int j = 0;
  #pragma unroll
  for (int k=1;k<14;k++) if (blk >= J.start[k]) j = k;
  size_t idx = (size_t)(blk - J.start[j])*2048 + (size_t)tid*8;
  const f32x4* ps = (const f32x4*)(J.s[j] + idx);
  f32x4 a = ps[0], b = ps[1];
  s16x8 o;
  #pragma unroll
  for (int i=0;i<4;i++){ o[i]=(short)f2b(a[i]); o[4+i]=(short)f2b(b[i]); }
  *(s16x8*)(J.d[j] + idx) = o;
}

// ---------------- LayerNorm stats ----------------
__global__ __launch_bounds__(256) void ln_stats(const float* __restrict__ x,
                                                float* __restrict__ mu, float* __restrict__ rstd){
  int b = blockIdx.x;
  const float* xb = x + (size_t)b*32768;
  float s1=0.f, s2=0.f;
  for (int i = threadIdx.x*4; i < 32768; i += 256*4){
    f32x4 v = *(const f32x4*)(xb+i);
    #pragma unroll
    for (int j=0;j<4;j++){ float f = v[j]; s1+=f; s2+=f*f; }
  }
  #pragma unroll
  for (int o=32;o>0;o>>=1){ s1 += __shfl_down(s1,o); s2 += __shfl_down(s2,o); }
  __shared__ float r1[4], r2[4];
  int w = threadIdx.x>>6;
  if ((threadIdx.x&63)==0){ r1[w]=s1; r2[w]=s2; }
  __syncthreads();
  if (threadIdx.x==0){
    float a=0.f,c=0.f;
    for (int i=0;i<4;i++){ a+=r1[i]; c+=r2[i]; }
    float m=a/32768.f, v=c/32768.f-m*m;
    mu[b]=m; rstd[b]=1.f/sqrtf(v+1e-5f);
  }
}

// ---------------- fused LN + encode GEMM ----------------
__global__ __launch_bounds__(256) void ln_gemm(const float* __restrict__ x,
    const float* __restrict__ mu, const float* __restrict__ rstd,
    const float* __restrict__ g, const float* __restrict__ bn,
    const u16* __restrict__ Wb, const float* __restrict__ be, u16* __restrict__ xe){
  __shared__ __align__(16) u16 As[128*32];
  __shared__ __align__(16) u16 Ws[128*32];
  int tid=threadIdx.x, lane=tid&63, wid=tid>>6;
  int wr=wid>>1, wc=wid&1;
  long m0=(long)blockIdx.y*128, n0=(long)blockIdx.x*128;
  int lr=lane&15, lk=(lane>>4)*8;
  f32x4 acc[4][4];
  #pragma unroll
  for (int i=0;i<4;i++)
    #pragma unroll
    for (int j=0;j<4;j++) acc[i][j]=(f32x4){0.f,0.f,0.f,0.f};

  for (int k0=0;k0<128;k0+=32){
    __syncthreads();
    #pragma unroll
    for (int c=tid;c<512;c+=256){
      int row=c>>2, kb=(c&3)*8;
      long R=m0+row;
      int b=(int)(R>>8), tt=(int)(R&255);
      float m=mu[b], rs=rstd[b];
      const f32x4* px=(const f32x4*)(x + R*128 + k0+kb);
      const f32x4* pg=(const f32x4*)(g + tt*128 + k0+kb);
      const f32x4* pb=(const f32x4*)(bn + tt*128 + k0+kb);
      f32x4 x0=px[0], x1=px[1], g0=pg[0], g1=pg[1], b0=pb[0], b1=pb[1];
      s16x8 o;
      #pragma unroll
      for (int j=0;j<4;j++){
        o[j]   = (short)f2b((x0[j]-m)*rs*g0[j] + b0[j]);
        o[4+j] = (short)f2b((x1[j]-m)*rs*g1[j] + b1[j]);
      }
      *(s16x8*)(As + row*32 + kb) = o;
    }
    #pragma unroll
    for (int c=tid;c<512;c+=256){
      int row=c>>2, kb=(c&3)*8;
      *(s16x8*)(Ws + row*32 + kb) = *(const s16x8*)(Wb + (n0+row)*128 + k0+kb);
    }
    __syncthreads();
    bv8 af[4], bf[4];
    #pragma unroll
    for (int i=0;i<4;i++) af[i] = ldf(As + (wr*64+i*16+lr)*32 + lk);
    #pragma unroll
    for (int j=0;j<4;j++) bf[j] = ldf(Ws + (wc*64+j*16+lr)*32 + lk);
    #pragma unroll
    for (int i=0;i<4;i++)
      #pragma unroll
      for (int j=0;j<4;j++) acc[i][j] = mfma16(af[i], bf[j], acc[i][j]);
  }
  #pragma unroll
  for (int i=0;i<4;i++)
    #pragma unroll
    for (int j=0;j<4;j++)
      #pragma unroll
      for (int r=0;r<4;r++){
        int m = wr*64+i*16+(lane>>4)*4+r;
        int n = wc*64+j*16+lr;
        float v = acc[i][j][r] + be[n0+n];
        xe[(m0+m)*256 + n0+n] = f2b(fmaxf(v,0.f));
      }
}

// ---------------- generic GEMM ----------------
template<int BM, int BN, bool RELU, bool OUTF32>
__global__ __launch_bounds__(256) void gemm_bt(const u16* __restrict__ A, int lda,
                                               const u16* __restrict__ W, int ldw,
                                               const float* __restrict__ bias1, const float* __restrict__ bias2,
                                               u16* __restrict__ Cb, float* __restrict__ Cf, int ldc, int K){
  constexpr int BK=32;
  constexpr int FM=BM/32, FN=BN/32;
  __shared__ __align__(16) u16 As[BM*BK];
  __shared__ __align__(16) u16 Ws[BN*BK];
  int tid=threadIdx.x, lane=tid&63, wid=tid>>6;
  int wr=wid>>1, wc=wid&1;
  long m0=(long)blockIdx.y*BM, n0=(long)blockIdx.x*BN;
  int lr=lane&15, lk=(lane>>4)*8;
  f32x4 acc[FM][FN];
  #pragma unroll
  for (int i=0;i<FM;i++)
    #pragma unroll
    for (int j=0;j<FN;j++) acc[i][j] = (f32x4){0.f,0.f,0.f,0.f};
  for (int k0=0;k0<K;k0+=BK){
    __syncthreads();
    #pragma unroll
    for (int c=tid;c<BM*4;c+=256){
      int row=c>>2, kb=(c&3)*8;
      *(s16x8*)(As + row*BK + kb) = *(const s16x8*)(A + (m0+row)*lda + k0+kb);
    }
    #pragma unroll
    for (int c=tid;c<BN*4;c+=256){
      int row=c>>2, kb=(c&3)*8;
      *(s16x8*)(Ws + row*BK + kb) = *(const s16x8*)(W + (n0+row)*ldw + k0+kb);
    }
    __syncthreads();
    bv8 af[FM], bf[FN];
    #pragma unroll
    for (int i=0;i<FM;i++) af[i] = ldf(As + (wr*(BM/2)+i*16+lr)*BK + lk);
    #pragma unroll
    for (int j=0;j<FN;j++) bf[j] = ldf(Ws + (wc*(BN/2)+j*16+lr)*BK + lk);
    #pragma unroll
    for (int i=0;i<FM;i++)
      #pragma unroll
      for (int j=0;j<FN;j++) acc[i][j] = mfma16(af[i], bf[j], acc[i][j]);
  }
  #pragma unroll
  for (int i=0;i<FM;i++)
    #pragma unroll
    for (int j=0;j<FN;j++)
      #pragma unroll
      for (int r=0;r<4;r++){
        int m = wr*(BM/2)+i*16+(lane>>4)*4+r;
        int n = wc*(BN/2)+j*16+lr;
        float v = acc[i][j][r];
        if (bias1) v += bias1[n0+n];
        if (bias2) v += bias2[n0+n];
        if (RELU) v = fmaxf(v,0.f);
        if (OUTF32) Cf[(m0+m)*ldc + n0+n] = v;
        else        Cb[(m0+m)*ldc + n0+n] = f2b(v);
      }
}

// ================= persistent encoder (both dirs, all 256 steps, pooling fused) =================
// grid 256: dir=bx>>7, bt=(bx>>5)&3 (128 samples), kc=bx&31 (16 cells / 64 gate rows)
struct EncP {
  const u16 *xe; const int* lens;
  const u16 *Wihf,*Whhf,*Wihb,*Whhb;
  const float *bif,*bhf,*bib,*bhb;
  u16 *hf0,*hf1,*hb0,*hb1,*pooled;
  unsigned* bar;
};

__global__ __launch_bounds__(256,1) void enc_persist(EncP P){
  __shared__ __align__(16) u16 Wl[64*776];   // [64 gate rows][768 K] pad->776
  __shared__ __align__(16) u16 As[128*72];   // [128 samples][64 K] pad->72
  int bx=blockIdx.x, tid=threadIdx.x, lane=tid&63, w=tid>>6;
  int dir=bx>>7, bt=(bx>>5)&3, kc=bx&31;
  int lr=lane&15, lk=(lane>>4)*8;
  unsigned* cnt = P.bar + (bx>>5)*32;        // group = dir*4+bt, 128B apart
  const u16* Wih = dir? P.Wihb : P.Wihf;
  const u16* Whh = dir? P.Whhb : P.Whhf;
  const float* bi = dir? P.bib : P.bif;
  const float* bh = dir? P.bhb : P.bhf;
  u16* hb0 = dir? P.hb0 : P.hf0;
  u16* hb1 = dir? P.hb1 : P.hf1;

  // stage weights once: row = g*16+c -> global gate row g*512 + kc*16 + c
  for (int idx=tid; idx<64*96; idx+=256){
    int row=idx/96, col=(idx%96)*8;
    int g=row>>4, c=row&15;
    size_t grow=(size_t)(g*512 + kc*16 + c);
    const u16* src = (col<256)? (Wih + grow*256 + col) : (Whh + grow*512 + (col-256));
    *(s16x8*)(Wl + row*776 + col) = *(const s16x8*)src;
  }
  int cg = kc*16 + lr;
  float b_i = bi[cg]+bh[cg], b_f=bi[512+cg]+bh[512+cg];
  float b_g = bi[1024+cg]+bh[1024+cg], b_o=bi[1536+cg]+bh[1536+cg];
  int row_s = tid>>1, c0s=(tid&1)*32;
  int slen = P.lens[bt*128+row_s];
  size_t abase = (size_t)(bt*128+row_s);
  int elen[2][4];
  float cs[2][4], hh[2][4], asum[2][4];
  #pragma unroll
  for (int i=0;i<2;i++)
    #pragma unroll
    for (int r=0;r<4;r++){
      int m = w*32+i*16+(lane>>4)*4+r;
      elen[i][r] = P.lens[bt*128+m];
      cs[i][r]=0.f; hh[i][r]=0.f; asum[i][r]=0.f;
    }

  for (int t=0;t<256;t++){
    const u16* hp = (t&1)? hb1 : hb0;
    u16*       hn = (t&1)? hb0 : hb1;
    int tt = dir? max(slen-1-t,0) : t;
    const u16* xrow = P.xe + (abase*256 + (size_t)tt)*256;
    const u16* hrow = hp + abase*512;
    f32x4 acc[2][4];
    #pragma unroll
    for (int i=0;i<2;i++)
      #pragma unroll
      for (int g=0;g<4;g++) acc[i][g]=(f32x4){0.f,0.f,0.f,0.f};

    for (int kit=0;kit<12;kit++){
      int k0=kit*64;
      __syncthreads();
      #pragma unroll
      for (int j=0;j<4;j++){
        int col=c0s+j*8, gk=k0+col;
        const u16* src = (gk<256)? (xrow+gk) : (hrow + (gk-256));
        *(s16x8*)(As + row_s*72 + col) = *(const s16x8*)src;
      }
      __syncthreads();
      #pragma unroll
      for (int kk=0;kk<2;kk++){
        bv8 a0=ldf(As+(w*32+lr)*72+kk*32+lk), a1=ldf(As+(w*32+16+lr)*72+kk*32+lk);
        #pragma unroll
        for (int g=0;g<4;g++){
          bv8 bf=ldf(Wl+(g*16+lr)*776 + k0+kk*32+lk);
          acc[0][g]=mfma16(a0,bf,acc[0][g]);
          acc[1][g]=mfma16(a1,bf,acc[1][g]);
        }
      }
    }
    #pragma unroll
    for (int i=0;i<2;i++)
      #pragma unroll
      for (int r=0;r<4;r++){
        int m=w*32+i*16+(lane>>4)*4+r;
        if (t<elen[i][r]){
          float iv=sigm(acc[i][0][r]+b_i), fv=sigm(acc[i][1][r]+b_f);
          float gv=tanhf(acc[i][2][r]+b_g), ov=sigm(acc[i][3][r]+b_o);
          float c2=fv*cs[i][r]+iv*gv; float h2=ov*tanhf(c2);
          cs[i][r]=c2; hh[i][r]=h2; asum[i][r]+=h2;
        }
        hn[(size_t)(bt*128+m)*512 + cg] = f2b(hh[i][r]);
      }
    gbar(cnt, 32u*(unsigned)(t+1));
  }
  #pragma unroll
  for (int i=0;i<2;i++)
    #pragma unroll
    for (int r=0;r<4;r++){
      int m=w*32+i*16+(lane>>4)*4+r;
      P.pooled[(size_t)(bt*128+m)*1024 + (size_t)dir*512 + cg] = f2b(asum[i][r]/(float)elen[i][r]);
    }
}

// ================= persistent decoder (LSTM + FFN, all 256 steps) =================
// grid 128: bt=bx>>5 (128 samples), kc=bx&31 (16 cells)
// phases: P1 all blocks LSTM -> h_t; P2 kc<16 FFN1 -> hmid; P3 kc in[16,24) FFN2 -> pose + out
struct DecP {
  const u16 *Wihd,*Whhd; const float* gix;
  const u16 *W1d; const float* b1d;
  const u16 *W2d; const float* b2d;
  u16 *h0,*h1,*pose,*hmid;
  float* outd;
  unsigned* bar;
};

__global__ __launch_bounds__(256,1) void dec_persist(DecP P){
  __shared__ __align__(16) u16 Wl[64*648];   // [64 gate rows][640 K] pad->648
  __shared__ __align__(16) u16 As[128*72];
  __shared__ __align__(16) u16 F1[16*520];   // W1d slice [16][512] pad->520
  __shared__ __align__(16) u16 F2[16*264];   // W2d slice [16][256] pad->264
  int bx=blockIdx.x, tid=threadIdx.x, lane=tid&63, w=tid>>6;
  int bt=bx>>5, kc=bx&31;
  int lr=lane&15, lk=(lane>>4)*8;
  unsigned* cnt = P.bar + (8+bt)*32;

  // LSTM weights: row g*16+c -> gate row g*512+kc*16+c; cols: [0,128)=Wih_d[:,256+..], [128,640)=Whh_d
  for (int idx=tid; idx<64*80; idx+=256){
    int row=idx/80, col=(idx%80)*8;
    int g=row>>4, c=row&15;
    size_t grow=(size_t)(g*512 + kc*16 + c);
    const u16* src = (col<128)? (P.Wihd + grow*384 + 256 + col) : (P.Whhd + grow*512 + (col-128));
    *(s16x8*)(Wl + row*648 + col) = *(const s16x8*)src;
  }
  if (kc<16){
    for (int idx=tid; idx<16*64; idx+=256){
      int rr=idx>>6, col=(idx&63)*8;
      *(s16x8*)(F1 + rr*520 + col) = *(const s16x8*)(P.W1d + (size_t)(kc*16+rr)*512 + col);
    }
  } else if (kc<24){
    for (int idx=tid; idx<16*32; idx+=256){
      int rr=idx>>5, col=(idx&31)*8;
      *(s16x8*)(F2 + rr*264 + col) = *(const s16x8*)(P.W2d + (size_t)((kc-16)*16+rr)*256 + col);
    }
  }
  // gix -> registers (step-invariant gate bias incl. both biases)
  float gx[2][4][4];
  #pragma unroll
  for (int i=0;i<2;i++)
    #pragma unroll
    for (int g=0;g<4;g++)
      #pragma unroll
      for (int r=0;r<4;r++){
        int m=w*32+i*16+(lane>>4)*4+r;
        gx[i][g][r] = P.gix[(size_t)(bt*128+m)*2048 + (size_t)g*512 + kc*16 + lr];
      }
  float b1 = (kc<16)? P.b1d[kc*16+lr] : 0.f;
  float b2 = (kc>=16&&kc<24)? P.b2d[(kc-16)*16+lr] : 0.f;
  int row_s = tid>>1, c0s=(tid&1)*32;
  size_t abase = (size_t)(bt*128+row_s);
  float cs[2][4];
  #pragma unroll
  for (int i=0;i<2;i++)
    #pragma unroll
    for (int r=0;r<4;r++) cs[i][r]=0.f;

  unsigned bar_n = 0;
  for (int t=0;t<256;t++){
    const u16* hp = (t&1)? P.h1 : P.h0;
    u16*       hn = (t&1)? P.h0 : P.h1;
    // ---- P1: LSTM ----
    {
      const u16* prow = P.pose + abase*128;
      const u16* hrow = hp + abase*512;
      f32x4 acc[2][4];
      #pragma unroll
      for (int i=0;i<2;i++)
        #pragma unroll
        for (int g=0;g<4;g++) acc[i][g]=(f32x4){gx[i][g][0],gx[i][g][1],gx[i][g][2],gx[i][g][3]};
      for (int kit=0;kit<10;kit++){
        int k0=kit*64;
        __syncthreads();
        #pragma unroll
        for (int j=0;j<4;j++){
          int col=c0s+j*8, gk=k0+col;
          const u16* src = (gk<128)? (prow+gk) : (hrow + (gk-128));
          *(s16x8*)(As + row_s*72 + col) = *(const s16x8*)src;
        }
        __syncthreads();
        #pragma unroll
        for (int kk=0;kk<2;kk++){
          bv8 a0=ldf(As+(w*32+lr)*72+kk*32+lk), a1=ldf(As+(w*32+16+lr)*72+kk*32+lk);
          #pragma unroll
          for (int g=0;g<4;g++){
            bv8 bf=ldf(Wl+(g*16+lr)*648 + k0+kk*32+lk);
            acc[0][g]=mfma16(a0,bf,acc[0][g]);
            acc[1][g]=mfma16(a1,bf,acc[1][g]);
          }
        }
      }
      #pragma unroll
      for (int i=0;i<2;i++)
        #pragma unroll
        for (int r=0;r<4;r++){
          int m=w*32+i*16+(lane>>4)*4+r;
          float iv=sigm(acc[i][0][r]), fv=sigm(acc[i][1][r]);
          float gv=tanhf(acc[i][2][r]), ov=sigm(acc[i][3][r]);
          float c2=fv*cs[i][r]+iv*gv; float h2=ov*tanhf(c2);
          cs[i][r]=c2;
          hn[(size_t)(bt*128+m)*512 + kc*16+lr] = f2b(h2);
        }
    }
    gbar(cnt, 32u*(++bar_n));
    // ---- P2: FFN1 (blocks kc<16): hmid = relu(h_t @ W1d_slice^T + b1d) ----
    if (kc<16){
      const u16* hrow = hn + abase*512;
      f32x4 a2[2]; a2[0]=(f32x4){0,0,0,0}; a2[1]=(f32x4){0,0,0,0};
      for (int kit=0;kit<8;kit++){
        int k0=kit*64;
        __syncthreads();
        #pragma unroll
        for (int j=0;j<4;j++){
          int col=c0s+j*8;
          *(s16x8*)(As + row_s*72 + col) = *(const s16x8*)(hrow + k0+col);
        }
        __syncthreads();
        #pragma unroll
        for (int kk=0;kk<2;kk++){
          bv8 a0=ldf(As+(w*32+lr)*72+kk*32+lk), a1=ldf(As+(w*32+16+lr)*72+kk*32+lk);
          bv8 bf=ldf(F1 + lr*520 + k0+kk*32+lk);
          a2[0]=mfma16(a0,bf,a2[0]);
          a2[1]=mfma16(a1,bf,a2[1]);
        }
      }
      #pragma unroll
      for (int i=0;i<2;i++)
        #pragma unroll
        for (int r=0;r<4;r++){
          int m=w*32+i*16+(lane>>4)*4+r;
          float v = a2[i][r] + b1;
          P.hmid[(size_t)(bt*128+m)*256 + kc*16+lr] = f2b(fmaxf(v,0.f));
        }
    }
    gbar(cnt, 32u*(++bar_n));
    // ---- P3: FFN2 (blocks 16..23): pose = hmid @ W2d_slice^T + b2d ----
    if (kc>=16 && kc<24){
      const u16* mrow = P.hmid + abase*256;
      f32x4 a3[2]; a3[0]=(f32x4){0,0,0,0}; a3[1]=(f32x4){0,0,0,0};
      for (int kit=0;kit<4;kit++){
        int k0=kit*64;
        __syncthreads();
        #pragma unroll
        for (int j=0;j<4;j++){
          int col=c0s+j*8;
          *(s16x8*)(As + row_s*72 + col) = *(const s16x8*)(mrow + k0+col);
        }
        __syncthreads();
        #pragma unroll
        for (int kk=0;kk<2;kk++){
          bv8 a0=ldf(As+(w*32+lr)*72+kk*32+lk), a1=ldf(As+(w*32+16+lr)*72+kk*32+lk);
          bv8 bf=ldf(F2 + lr*264 + k0+kk*32+lk);
          a3[0]=mfma16(a0,bf,a3[0]);
          a3[1]=mfma16(a1,bf,a3[1]);
        }
      }
      int pc = (kc-16)*16 + lr;
      #pragma unroll
      for (int i=0;i<2;i++)
        #pragma unroll
        for (int r=0;r<4;r++){
          int m=w*32+i*16+(lane>>4)*4+r;
          float v = a3[i][r] + b2;
          P.pose[(size_t)(bt*128+m)*128 + pc] = f2b(v);
          P.outd[(size_t)(bt*128+m)*32768 + (size_t)t*128 + pc] = v;
        }
    }
    gbar(cnt, 32u*(++bar_n));
  }
}

__global__ __launch_bounds__(512) void len_cast(const int* __restrict__ lens, float* __restrict__ out){
  int i = threadIdx.x;
  if (i < 512) out[i] = (float)lens[i];
}

// ============================== host ==============================
extern "C" void kernel_launch(void* const* d_in, const int* in_sizes, int n_in,
                              void* d_out, int out_size, void* d_ws, size_t ws_size,
                              hipStream_t stream){
  (void)in_sizes; (void)n_in; (void)out_size; (void)ws_size;
  const float* x      = (const float*)d_in[0];
  const int*   lens   = (const int*)d_in[1];
  const float* ng     = (const float*)d_in[2];
  const float* nb     = (const float*)d_in[3];
  const float* We     = (const float*)d_in[4];
  const float* be     = (const float*)d_in[5];
  const float* Wih_f  = (const float*)d_in[6];
  const float* Whh_f  = (const float*)d_in[7];
  const float* bih_f  = (const float*)d_in[8];
  const float* bhh_f  = (const float*)d_in[9];
  const float* Wih_b  = (const float*)d_in[10];
  const float* Whh_b  = (const float*)d_in[11];
  const float* bih_b  = (const float*)d_in[12];
  const float* bhh_b  = (const float*)d_in[13];
  const float* W1e    = (const float*)d_in[14];
  const float* b1e    = (const float*)d_in[15];
  const float* W2e    = (const float*)d_in[16];
  const float* b2e    = (const float*)d_in[17];
  const float* Wd     = (const float*)d_in[18];
  const float* bd     = (const float*)d_in[19];
  const float* Wp1    = (const float*)d_in[20];
  const float* bp1    = (const float*)d_in[21];
  const float* Wp2    = (const float*)d_in[22];
  const float* bp2    = (const float*)d_in[23];
  const float* Wih_d  = (const float*)d_in[24];
  const float* Whh_d  = (const float*)d_in[25];
  const float* bih_d  = (const float*)d_in[26];
  const float* bhh_d  = (const float*)d_in[27];
  const float* W1d    = (const float*)d_in[28];
  const float* b1d    = (const float*)d_in[29];
  const float* W2d    = (const float*)d_in[30];
  const float* b2d    = (const float*)d_in[31];

  char* p = (char*)d_ws;
  auto carve = [&](size_t bytes)->void*{ void* r=(void*)p; p += (bytes+255)&~(size_t)255; return r; };
  float* mu   = (float*)carve(512*4);
  float* rstd = (float*)carve(512*4);
  u16* xe     = (u16*)carve((size_t)33554432*2);
  u16* wWe  = (u16*)carve(32768*2);
  u16* wIhf = (u16*)carve(524288*2);
  u16* wHhf = (u16*)carve(1048576*2);
  u16* wIhb = (u16*)carve(524288*2);
  u16* wHhb = (u16*)carve(1048576*2);
  u16* wW1e = (u16*)carve(524288*2);
  u16* wW2e = (u16*)carve(131072*2);
  u16* wWd  = (u16*)carve(65536*2);
  u16* wWp1 = (u16*)carve(65536*2);
  u16* wWp2 = (u16*)carve(32768*2);
  u16* wIhd = (u16*)carve(786432*2);
  u16* wHhd = (u16*)carve(1048576*2);
  u16* wW1d = (u16*)carve(131072*2);
  u16* wW2d = (u16*)carve(32768*2);
  u16* hf0  = (u16*)carve(524288);
  u16* hf1  = (u16*)carve(524288);
  u16* hb0  = (u16*)carve(524288);
  u16* hb1  = (u16*)carve(524288);
  u16* hd0  = (u16*)carve(524288);
  u16* hd1  = (u16*)carve(524288);
  u16* pooled = (u16*)carve(1048576);
  u16* out1   = (u16*)carve(524288);
  u16* zlat   = (u16*)carve(262144);
  u16* x0     = (u16*)carve(262144);
  u16* t0     = (u16*)carve(262144);
  float* gix  = (float*)carve(4194304);
  u16* pose   = (u16*)carve(131072);
  u16* hmid   = (u16*)carve(262144);
  unsigned* barcnt = (unsigned*)carve(12*32*4);

  float* out_x   = (float*)d_out;
  float* out_dec = out_x + 16777216;
  float* out_len = out_x + 33554432;

  hipMemcpyAsync(out_x, x, (size_t)16777216*4, hipMemcpyDeviceToDevice, stream);
  hipMemsetAsync(hf0,0,524288,stream);
  hipMemsetAsync(hb0,0,524288,stream);
  hipMemsetAsync(hd0,0,524288,stream);
  hipMemsetAsync(barcnt,0,12*32*4,stream);

  CvtJobs J;
  const float* srcs[14] = {We,Wih_f,Whh_f,Wih_b,Whh_b,W1e,W2e,Wd,Wp1,Wp2,Wih_d,Whh_d,W1d,W2d};
  u16* dsts[14] = {wWe,wIhf,wHhf,wIhb,wHhb,wW1e,wW2e,wWd,wWp1,wWp2,wIhd,wHhd,wW1d,wW2d};
  int ns[14] = {32768,524288,1048576,524288,1048576,524288,131072,65536,65536,32768,786432,1048576,131072,32768};
  int blk=0;
  for (int i=0;i<14;i++){ J.s[i]=srcs[i]; J.d[i]=dsts[i]; J.start[i]=blk; blk += ns[i]/2048; }
  cvt_w<<<blk,256,0,stream>>>(J);

  ln_stats<<<512,256,0,stream>>>(x,mu,rstd);
  ln_gemm<<<dim3(2,1024),256,0,stream>>>(x,mu,rstd,ng,nb,wWe,be,xe);

  // persistent encoder (cooperative; fallback to plain launch)
  EncP EP = {xe,lens,wIhf,wHhf,wIhb,wHhb,bih_f,bhh_f,bih_b,bhh_b,hf0,hf1,hb0,hb1,pooled,barcnt};
  {
    void* ea[] = {&EP};
    if (hipLaunchCooperativeKernel((void*)enc_persist, dim3(256), dim3(256), ea, 0, stream) != hipSuccess)
      enc_persist<<<256,256,0,stream>>>(EP);
  }

  gemm_bt<64,64,true ,false><<<dim3(8,8),256,0,stream>>>(pooled,1024,wW1e,1024,b1e,nullptr,out1,nullptr,512,1024);
  gemm_bt<64,64,false,false><<<dim3(4,8),256,0,stream>>>(out1,512,wW2e,512,b2e,nullptr,zlat,nullptr,256,512);
  gemm_bt<64,64,true ,false><<<dim3(4,8),256,0,stream>>>(zlat,256,wWd,256,bd,nullptr,x0,nullptr,256,256);
  gemm_bt<64,64,true ,false><<<dim3(4,8),256,0,stream>>>(x0,256,wWp1,256,bp1,nullptr,t0,nullptr,256,256);
  gemm_bt<64,64,false,false><<<dim3(2,8),256,0,stream>>>(t0,256,wWp2,256,bp2,nullptr,pose,nullptr,128,256);
  gemm_bt<64,128,false,true><<<dim3(16,8),256,0,stream>>>(x0,256,wIhd,384,bih_d,bhh_d,nullptr,gix,2048,256);

  // persistent decoder
  DecP DP = {wIhd,wHhd,gix,wW1d,b1d,wW2d,b2d,hd0,hd1,pose,hmid,out_dec,barcnt};
  {
    void* da[] = {&DP};
    if (hipLaunchCooperativeKernel((void*)dec_persist, dim3(128), dim3(256), da, 0, stream) != hipSuccess)
      dec_persist<<<128,256,0,stream>>>(DP);
  }

  len_cast<<<1,512,0,stream>>>(lens,out_len);
}

// Round 4
// 10451.785 us; speedup vs baseline: 2.5919x; 2.5919x over previous
//
#include <hip/hip_runtime.h>
#include <stdint.h>
#include <math.h>

typedef unsigned short u16;
typedef unsigned long long u64;
typedef short s16x8 __attribute__((ext_vector_type(8)));
typedef __bf16 bv8 __attribute__((ext_vector_type(8)));
typedef float f32x4 __attribute__((ext_vector_type(4)));

#define DEV static __device__ __forceinline__

DEV float b2f(u16 x){ union{unsigned u; float f;} v; v.u=((unsigned)x)<<16; return v.f; }
DEV u16 f2b(float f){ union{float f; unsigned u;} v; v.f=f; unsigned u=v.u; u += 0x7fff + ((u>>16)&1u); return (u16)(u>>16); }
DEV float sigm(float x){ return 1.f/(1.f+expf(-x)); }
DEV f32x4 mfma16(bv8 a, bv8 b, f32x4 c){ return __builtin_amdgcn_mfma_f32_16x16x32_bf16(a,b,c,0,0,0); }
DEV bv8 ldf(const u16* p){ return __builtin_bit_cast(bv8, *(const s16x8*)p); }

// ---- coherence-light cross-block primitives (state via L3, no cache-maintenance) ----
DEV u64 ald8(const void* p){ return __hip_atomic_load((const u64*)p, __ATOMIC_RELAXED, __HIP_MEMORY_SCOPE_AGENT); }
DEV void ast8(void* p, u64 v){ __hip_atomic_store((u64*)p, v, __ATOMIC_RELAXED, __HIP_MEMORY_SCOPE_AGENT); }
DEV unsigned ald4(const unsigned* p){ return __hip_atomic_load(p, __ATOMIC_RELAXED, __HIP_MEMORY_SCOPE_AGENT); }

DEV void arrive(unsigned* flags, int my, unsigned e){
  asm volatile("s_waitcnt vmcnt(0)" ::: "memory");   // each thread drains its stores to the coherence point
  __syncthreads();                                    // all threads drained
  if (threadIdx.x==0)
    __hip_atomic_store(&flags[my*32], e, __ATOMIC_RELEASE, __HIP_MEMORY_SCOPE_AGENT);
}
DEV void waitflags(unsigned* flags, int lo, int n, unsigned e){
  int t = (int)threadIdx.x;
  if (t>=lo && t<lo+n){
    while (ald4(&flags[t*32]) < e) __builtin_amdgcn_s_sleep(4);
  }
  __syncthreads();
}

// ---------------- weight f32 -> bf16 conversion ----------------
struct CvtJobs { const float* s[14]; u16* d[14]; int start[14]; };

__global__ __launch_bounds__(256) void cvt_w(CvtJobs J){
  int blk = blockIdx.x, tid = threadIdx.x;
  int j = 0;
  #pragma unroll
  for (int k=1;k<14;k++) if (blk >= J.start[k]) j = k;
  size_t idx = (size_t)(blk - J.start[j])*2048 + (size_t)tid*8;
  const f32x4* ps = (const f32x4*)(J.s[j] + idx);
  f32x4 a = ps[0], b = ps[1];
  s16x8 o;
  #pragma unroll
  for (int i=0;i<4;i++){ o[i]=(short)f2b(a[i]); o[4+i]=(short)f2b(b[i]); }
  *(s16x8*)(J.d[j] + idx) = o;
}

// ---------------- LayerNorm stats ----------------
__global__ __launch_bounds__(256) void ln_stats(const float* __restrict__ x,
                                                float* __restrict__ mu, float* __restrict__ rstd){
  int b = blockIdx.x;
  const float* xb = x + (size_t)b*32768;
  float s1=0.f, s2=0.f;
  for (int i = threadIdx.x*4; i < 32768; i += 256*4){
    f32x4 v = *(const f32x4*)(xb+i);
    #pragma unroll
    for (int j=0;j<4;j++){ float f = v[j]; s1+=f; s2+=f*f; }
  }
  #pragma unroll
  for (int o=32;o>0;o>>=1){ s1 += __shfl_down(s1,o); s2 += __shfl_down(s2,o); }
  __shared__ float r1[4], r2[4];
  int w = threadIdx.x>>6;
  if ((threadIdx.x&63)==0){ r1[w]=s1; r2[w]=s2; }
  __syncthreads();
  if (threadIdx.x==0){
    float a=0.f,c=0.f;
    for (int i=0;i<4;i++){ a+=r1[i]; c+=r2[i]; }
    float m=a/32768.f, v=c/32768.f-m*m;
    mu[b]=m; rstd[b]=1.f/sqrtf(v+1e-5f);
  }
}

// ---------------- fused LN + encode GEMM ----------------
__global__ __launch_bounds__(256) void ln_gemm(const float* __restrict__ x,
    const float* __restrict__ mu, const float* __restrict__ rstd,
    const float* __restrict__ g, const float* __restrict__ bn,
    const u16* __restrict__ Wb, const float* __restrict__ be, u16* __restrict__ xe){
  __shared__ __align__(16) u16 As[128*32];
  __shared__ __align__(16) u16 Ws[128*32];
  int tid=threadIdx.x, lane=tid&63, wid=tid>>6;
  int wr=wid>>1, wc=wid&1;
  long m0=(long)blockIdx.y*128, n0=(long)blockIdx.x*128;
  int lr=lane&15, lk=(lane>>4)*8;
  f32x4 acc[4][4];
  #pragma unroll
  for (int i=0;i<4;i++)
    #pragma unroll
    for (int j=0;j<4;j++) acc[i][j]=(f32x4){0.f,0.f,0.f,0.f};

  for (int k0=0;k0<128;k0+=32){
    __syncthreads();
    #pragma unroll
    for (int c=tid;c<512;c+=256){
      int row=c>>2, kb=(c&3)*8;
      long R=m0+row;
      int b=(int)(R>>8), tt=(int)(R&255);
      float m=mu[b], rs=rstd[b];
      const f32x4* px=(const f32x4*)(x + R*128 + k0+kb);
      const f32x4* pg=(const f32x4*)(g + tt*128 + k0+kb);
      const f32x4* pb=(const f32x4*)(bn + tt*128 + k0+kb);
      f32x4 x0=px[0], x1=px[1], g0=pg[0], g1=pg[1], b0=pb[0], b1=pb[1];
      s16x8 o;
      #pragma unroll
      for (int j=0;j<4;j++){
        o[j]   = (short)f2b((x0[j]-m)*rs*g0[j] + b0[j]);
        o[4+j] = (short)f2b((x1[j]-m)*rs*g1[j] + b1[j]);
      }
      *(s16x8*)(As + row*32 + kb) = o;
    }
    #pragma unroll
    for (int c=tid;c<512;c+=256){
      int row=c>>2, kb=(c&3)*8;
      *(s16x8*)(Ws + row*32 + kb) = *(const s16x8*)(Wb + (n0+row)*128 + k0+kb);
    }
    __syncthreads();
    bv8 af[4], bf[4];
    #pragma unroll
    for (int i=0;i<4;i++) af[i] = ldf(As + (wr*64+i*16+lr)*32 + lk);
    #pragma unroll
    for (int j=0;j<4;j++) bf[j] = ldf(Ws + (wc*64+j*16+lr)*32 + lk);
    #pragma unroll
    for (int i=0;i<4;i++)
      #pragma unroll
      for (int j=0;j<4;j++) acc[i][j] = mfma16(af[i], bf[j], acc[i][j]);
  }
  #pragma unroll
  for (int i=0;i<4;i++)
    #pragma unroll
    for (int j=0;j<4;j++)
      #pragma unroll
      for (int r=0;r<4;r++){
        int m = wr*64+i*16+(lane>>4)*4+r;
        int n = wc*64+j*16+lr;
        float v = acc[i][j][r] + be[n0+n];
        xe[(m0+m)*256 + n0+n] = f2b(fmaxf(v,0.f));
      }
}

// ---------------- generic GEMM ----------------
template<int BM, int BN, bool RELU, bool OUTF32>
__global__ __launch_bounds__(256) void gemm_bt(const u16* __restrict__ A, int lda,
                                               const u16* __restrict__ W, int ldw,
                                               const float* __restrict__ bias1, const float* __restrict__ bias2,
                                               u16* __restrict__ Cb, float* __restrict__ Cf, int ldc, int K){
  constexpr int BK=32;
  constexpr int FM=BM/32, FN=BN/32;
  __shared__ __align__(16) u16 As[BM*BK];
  __shared__ __align__(16) u16 Ws[BN*BK];
  int tid=threadIdx.x, lane=tid&63, wid=tid>>6;
  int wr=wid>>1, wc=wid&1;
  long m0=(long)blockIdx.y*BM, n0=(long)blockIdx.x*BN;
  int lr=lane&15, lk=(lane>>4)*8;
  f32x4 acc[FM][FN];
  #pragma unroll
  for (int i=0;i<FM;i++)
    #pragma unroll
    for (int j=0;j<FN;j++) acc[i][j] = (f32x4){0.f,0.f,0.f,0.f};
  for (int k0=0;k0<K;k0+=BK){
    __syncthreads();
    #pragma unroll
    for (int c=tid;c<BM*4;c+=256){
      int row=c>>2, kb=(c&3)*8;
      *(s16x8*)(As + row*BK + kb) = *(const s16x8*)(A + (m0+row)*lda + k0+kb);
    }
    #pragma unroll
    for (int c=tid;c<BN*4;c+=256){
      int row=c>>2, kb=(c&3)*8;
      *(s16x8*)(Ws + row*BK + kb) = *(const s16x8*)(W + (n0+row)*ldw + k0+kb);
    }
    __syncthreads();
    bv8 af[FM], bf[FN];
    #pragma unroll
    for (int i=0;i<FM;i++) af[i] = ldf(As + (wr*(BM/2)+i*16+lr)*BK + lk);
    #pragma unroll
    for (int j=0;j<FN;j++) bf[j] = ldf(Ws + (wc*(BN/2)+j*16+lr)*BK + lk);
    #pragma unroll
    for (int i=0;i<FM;i++)
      #pragma unroll
      for (int j=0;j<FN;j++) acc[i][j] = mfma16(af[i], bf[j], acc[i][j]);
  }
  #pragma unroll
  for (int i=0;i<FM;i++)
    #pragma unroll
    for (int j=0;j<FN;j++)
      #pragma unroll
      for (int r=0;r<4;r++){
        int m = wr*(BM/2)+i*16+(lane>>4)*4+r;
        int n = wc*(BN/2)+j*16+lr;
        float v = acc[i][j][r];
        if (bias1) v += bias1[n0+n];
        if (bias2) v += bias2[n0+n];
        if (RELU) v = fmaxf(v,0.f);
        if (OUTF32) Cf[(m0+m)*ldc + n0+n] = v;
        else        Cb[(m0+m)*ldc + n0+n] = f2b(v);
      }
}

// ================= persistent encoder =================
// grid 256: grp = bx&7 (dir*4+bt, XCD-contiguous), kc = bx>>3 (16 cells)
struct EncP {
  const u16* xe; const int* lens;
  const u16 *Wihf,*Whhf,*Wihb,*Whhb;
  const float *bif,*bhf,*bib,*bhb;
  u16 *hf0,*hf1,*hb0,*hb1,*pooled;
  unsigned* flags;
};

__global__ __launch_bounds__(256,1) void enc_persist(EncP P){
  __shared__ __align__(16) u16 Wl[64*776];
  __shared__ __align__(16) u16 As[128*72];
  __shared__ __align__(16) u16 Hs[128*16];
  const int tid=threadIdx.x, lane=tid&63, w=tid>>6;
  const int bx=blockIdx.x;
  const int grp=bx&7, kc=bx>>3;
  const int dir=grp>>2, bt=grp&3;
  const int lr=lane&15, lk=(lane>>4)*8;
  unsigned* flags = P.flags + grp*1024;
  const u16* Wih = dir? P.Wihb : P.Wihf;
  const u16* Whh = dir? P.Whhb : P.Whhf;
  const float* bi = dir? P.bib : P.bif;
  const float* bh = dir? P.bhb : P.bhf;
  u16* h0 = dir? P.hb0 : P.hf0;
  u16* h1 = dir? P.hb1 : P.hf1;

  for (int idx=tid; idx<64*96; idx+=256){
    int row=idx/96, col=(idx%96)*8;
    int g=row>>4, c=row&15;
    size_t grow=(size_t)(g*512 + kc*16 + c);
    const u16* src = (col<256)? (Wih + grow*256 + col) : (Whh + grow*512 + (col-256));
    *(s16x8*)(Wl + row*776 + col) = *(const s16x8*)src;
  }
  const int cg = kc*16 + lr;
  const float b_i=bi[cg]+bh[cg], b_f=bi[512+cg]+bh[512+cg];
  const float b_g=bi[1024+cg]+bh[1024+cg], b_o=bi[1536+cg]+bh[1536+cg];
  const int row_s=tid>>1, c0s=(tid&1)*32;
  const int slen = P.lens[bt*128+row_s];
  const size_t arow=(size_t)(bt*128+row_s);
  int elen[2][4]; float cs[2][4], hh[2][4], asum[2][4];
  #pragma unroll
  for (int i=0;i<2;i++)
    #pragma unroll
    for (int r=0;r<4;r++){
      int m=w*32+i*16+(lane>>4)*4+r;
      elen[i][r]=P.lens[bt*128+m];
      cs[i][r]=0.f; hh[i][r]=0.f; asum[i][r]=0.f;
    }

  auto stageX = [&](int tt, int k0){
    const u16* src = P.xe + (arow*256 + (size_t)tt)*256 + k0 + c0s;
    #pragma unroll
    for (int j=0;j<4;j++) *(s16x8*)(As + row_s*72 + c0s + j*8) = *(const s16x8*)(src + j*8);
  };
  auto ldh = [&](u64* r, const u16* hb, int k0){
    const u16* src = hb + arow*512 + k0 + c0s;
    #pragma unroll
    for (int j=0;j<8;j++) r[j] = ald8(src + j*4);
  };
  auto sth = [&](const u64* r){
    #pragma unroll
    for (int j=0;j<8;j++) *(u64*)(As + row_s*72 + c0s + j*4) = r[j];
  };
  auto kitmma = [&](f32x4 (&acc)[2][4], int cb){
    #pragma unroll
    for (int kk=0;kk<2;kk++){
      bv8 a0=ldf(As+(w*32+lr)*72+kk*32+lk);
      bv8 a1=ldf(As+(w*32+16+lr)*72+kk*32+lk);
      #pragma unroll
      for (int g=0;g<4;g++){
        bv8 bf=ldf(Wl+(g*16+lr)*776 + cb + kk*32+lk);
        acc[0][g]=mfma16(a0,bf,acc[0][g]);
        acc[1][g]=mfma16(a1,bf,acc[1][g]);
      }
    }
  };

  // initial x-part gates (t=0)
  f32x4 xacc[2][4];
  #pragma unroll
  for (int i=0;i<2;i++)
    #pragma unroll
    for (int g=0;g<4;g++) xacc[i][g]=(f32x4){0.f,0.f,0.f,0.f};
  {
    int tt = dir? (slen-1) : 0;
    for (int kit=0;kit<4;kit++){
      __syncthreads(); stageX(tt, kit*64); __syncthreads(); kitmma(xacc, kit*64);
    }
  }

  for (int t=0;t<256;t++){
    const u16* hp = (t&1)? h1 : h0;
    u16*       hn = (t&1)? h0 : h1;
    waitflags(flags, 0, 32, (unsigned)t);
    f32x4 acc[2][4];
    #pragma unroll
    for (int i=0;i<2;i++)
      #pragma unroll
      for (int g=0;g<4;g++) acc[i][g]=xacc[i][g];
    // h-part: 8 kits, register-pipelined staging
    u64 ra[8], rb[8];
    ldh(ra, hp, 0);
    #pragma unroll
    for (int k2=0;k2<4;k2++){
      __syncthreads(); sth(ra); ldh(rb, hp, (2*k2+1)*64);
      __syncthreads(); kitmma(acc, 256+(2*k2)*64);
      __syncthreads(); sth(rb); if (2*k2+2<8) ldh(ra, hp, (2*k2+2)*64);
      __syncthreads(); kitmma(acc, 256+(2*k2+1)*64);
    }
    #pragma unroll
    for (int i=0;i<2;i++)
      #pragma unroll
      for (int r=0;r<4;r++){
        int m=w*32+i*16+(lane>>4)*4+r;
        if (t<elen[i][r]){
          float iv=sigm(acc[i][0][r]+b_i), fv=sigm(acc[i][1][r]+b_f);
          float gv=tanhf(acc[i][2][r]+b_g), ov=sigm(acc[i][3][r]+b_o);
          float c2=fv*cs[i][r]+iv*gv, h2v=ov*tanhf(c2);
          cs[i][r]=c2; hh[i][r]=h2v; asum[i][r]+=h2v;
        }
        Hs[m*16+lr]=f2b(hh[i][r]);
      }
    __syncthreads();
    #pragma unroll
    for (int q=0;q<2;q++){
      int cc=tid*2+q, sm=cc>>2, pt=cc&3;
      ast8(hn + (size_t)(bt*128+sm)*512 + kc*16 + pt*4, *(const u64*)(Hs + sm*16 + pt*4));
    }
    arrive(flags, kc, (unsigned)(t+1));
    // overlap window: x-part gates for t+1
    #pragma unroll
    for (int i=0;i<2;i++)
      #pragma unroll
      for (int g=0;g<4;g++) xacc[i][g]=(f32x4){0.f,0.f,0.f,0.f};
    if (t<255){
      int tp=t+1;
      int tt = dir? max(slen-1-tp,0) : tp;
      for (int kit=0;kit<4;kit++){
        __syncthreads(); stageX(tt, kit*64); __syncthreads(); kitmma(xacc, kit*64);
      }
    }
  }
  #pragma unroll
  for (int i=0;i<2;i++)
    #pragma unroll
    for (int r=0;r<4;r++){
      int m=w*32+i*16+(lane>>4)*4+r;
      P.pooled[(size_t)(bt*128+m)*1024 + (size_t)dir*512 + cg]=f2b(asum[i][r]/(float)elen[i][r]);
    }
}

// ================= persistent decoder =================
// grid 128: bt = bx&3 (XCD-pair-contiguous), kc = bx>>2 (16 cells)
struct DecP {
  const u16 *Wihd,*Whhd; const float* gix;
  const u16* W1d; const float* b1d;
  const u16* W2d; const float* b2d;
  u16 *h0,*h1,*pose,*hmid;
  float* outd;
  unsigned* flags;
};

__global__ __launch_bounds__(256,1) void dec_persist(DecP P){
  __shared__ __align__(16) u16 Wl[64*648];
  __shared__ __align__(16) u16 As[128*72];
  __shared__ __align__(16) u16 F1[16*520];
  __shared__ __align__(16) u16 F2[16*264];
  __shared__ __align__(16) u16 Hs[128*16];
  const int tid=threadIdx.x, lane=tid&63, w=tid>>6;
  const int bx=blockIdx.x;
  const int bt=bx&3, kc=bx>>2;
  const int lr=lane&15, lk=(lane>>4)*8;
  unsigned* flags = P.flags + bt*1024;

  for (int idx=tid; idx<64*80; idx+=256){
    int row=idx/80, col=(idx%80)*8;
    int g=row>>4, c=row&15;
    size_t grow=(size_t)(g*512 + kc*16 + c);
    const u16* src = (col<128)? (P.Wihd + grow*384 + 256 + col) : (P.Whhd + grow*512 + (col-128));
    *(s16x8*)(Wl + row*648 + col) = *(const s16x8*)src;
  }
  if (kc<16){
    for (int idx=tid; idx<16*64; idx+=256){
      int rr=idx>>6, col=(idx&63)*8;
      *(s16x8*)(F1 + rr*520 + col) = *(const s16x8*)(P.W1d + (size_t)(kc*16+rr)*512 + col);
    }
  } else if (kc<24){
    for (int idx=tid; idx<16*32; idx+=256){
      int rr=idx>>5, col=(idx&31)*8;
      *(s16x8*)(F2 + rr*264 + col) = *(const s16x8*)(P.W2d + (size_t)((kc-16)*16+rr)*256 + col);
    }
  }
  float gx[2][4][4];
  #pragma unroll
  for (int i=0;i<2;i++)
    #pragma unroll
    for (int g=0;g<4;g++)
      #pragma unroll
      for (int r=0;r<4;r++){
        int m=w*32+i*16+(lane>>4)*4+r;
        gx[i][g][r]=P.gix[(size_t)(bt*128+m)*2048 + (size_t)g*512 + kc*16 + lr];
      }
  const float b1=(kc<16)? P.b1d[kc*16+lr] : 0.f;
  const float b2=(kc>=16&&kc<24)? P.b2d[(kc-16)*16+lr] : 0.f;
  const int row_s=tid>>1, c0s=(tid&1)*32;
  const size_t arow=(size_t)(bt*128+row_s);
  float cs[2][4];
  f32x4 gach[2][4];
  #pragma unroll
  for (int i=0;i<2;i++){
    #pragma unroll
    for (int r=0;r<4;r++) cs[i][r]=0.f;
    #pragma unroll
    for (int g=0;g<4;g++) gach[i][g]=(f32x4){0.f,0.f,0.f,0.f};
  }

  auto ldst8 = [&](const u16* base, int stride, int k0){
    const u16* src = base + arow*(size_t)stride + k0 + c0s;
    #pragma unroll
    for (int j=0;j<8;j++) *(u64*)(As + row_s*72 + c0s + j*4) = ald8(src + j*4);
  };
  auto ldh = [&](u64* r, const u16* hb, int k0){
    const u16* src = hb + arow*512 + k0 + c0s;
    #pragma unroll
    for (int j=0;j<8;j++) r[j] = ald8(src + j*4);
  };
  auto sth = [&](const u64* r){
    #pragma unroll
    for (int j=0;j<8;j++) *(u64*)(As + row_s*72 + c0s + j*4) = r[j];
  };
  auto kitgates = [&](f32x4 (&acc)[2][4], int cb){
    #pragma unroll
    for (int kk=0;kk<2;kk++){
      bv8 a0=ldf(As+(w*32+lr)*72+kk*32+lk);
      bv8 a1=ldf(As+(w*32+16+lr)*72+kk*32+lk);
      #pragma unroll
      for (int g=0;g<4;g++){
        bv8 bf=ldf(Wl+(g*16+lr)*648 + cb + kk*32+lk);
        acc[0][g]=mfma16(a0,bf,acc[0][g]);
        acc[1][g]=mfma16(a1,bf,acc[1][g]);
      }
    }
  };
  auto kitf1 = [&](f32x4 (&fa)[2], int cb){
    #pragma unroll
    for (int kk=0;kk<2;kk++){
      bv8 a0=ldf(As+(w*32+lr)*72+kk*32+lk);
      bv8 a1=ldf(As+(w*32+16+lr)*72+kk*32+lk);
      bv8 bf=ldf(F1 + lr*520 + cb + kk*32+lk);
      fa[0]=mfma16(a0,bf,fa[0]); fa[1]=mfma16(a1,bf,fa[1]);
    }
  };
  auto kitf2 = [&](f32x4 (&fa)[2], int cb){
    #pragma unroll
    for (int kk=0;kk<2;kk++){
      bv8 a0=ldf(As+(w*32+lr)*72+kk*32+lk);
      bv8 a1=ldf(As+(w*32+16+lr)*72+kk*32+lk);
      bv8 bf=ldf(F2 + lr*264 + cb + kk*32+lk);
      fa[0]=mfma16(a0,bf,fa[0]); fa[1]=mfma16(a1,bf,fa[1]);
    }
  };

  for (int t=0;t<256;t++){
    u16* hn = (t&1)? P.h0 : P.h1;
    // wait pose_t (from FFN2 blocks of step t-1)
    waitflags(flags, 16, 8, 3u*(unsigned)t);
    // ---- P1: gates = gix + gates_h(precomputed) + pose-part (K=128) ----
    f32x4 acc[2][4];
    #pragma unroll
    for (int i=0;i<2;i++)
      #pragma unroll
      for (int g=0;g<4;g++){
        f32x4 gv = (f32x4){gx[i][g][0],gx[i][g][1],gx[i][g][2],gx[i][g][3]};
        acc[i][g]=gach[i][g]+gv;
      }
    for (int kit=0;kit<2;kit++){
      __syncthreads(); ldst8(P.pose, 128, kit*64); __syncthreads(); kitgates(acc, kit*64);
    }
    #pragma unroll
    for (int i=0;i<2;i++)
      #pragma unroll
      for (int r=0;r<4;r++){
        float iv=sigm(acc[i][0][r]), fv=sigm(acc[i][1][r]);
        float gv=tanhf(acc[i][2][r]), ov=sigm(acc[i][3][r]);
        float c2=fv*cs[i][r]+iv*gv, h2v=ov*tanhf(c2);
        cs[i][r]=c2;
        int m=w*32+i*16+(lane>>4)*4+r;
        Hs[m*16+lr]=f2b(h2v);
      }
    __syncthreads();
    #pragma unroll
    for (int q=0;q<2;q++){
      int cc=tid*2+q, sm=cc>>2, pt=cc&3;
      ast8(hn + (size_t)(bt*128+sm)*512 + kc*16 + pt*4, *(const u64*)(Hs + sm*16 + pt*4));
    }
    arrive(flags, kc, 3u*t+1u);
    waitflags(flags, 0, 32, 3u*t+1u);
    // ---- combined: gates_h for t+1 (all blocks) + FFN1 (kc<16), K=512 over h2 ----
    f32x4 gn[2][4]; f32x4 fa[2];
    #pragma unroll
    for (int i=0;i<2;i++)
      #pragma unroll
      for (int g=0;g<4;g++) gn[i][g]=(f32x4){0.f,0.f,0.f,0.f};
    fa[0]=(f32x4){0.f,0.f,0.f,0.f}; fa[1]=fa[0];
    u64 ra[8], rb[8];
    ldh(ra, hn, 0);
    #pragma unroll
    for (int k2=0;k2<4;k2++){
      __syncthreads(); sth(ra); ldh(rb, hn, (2*k2+1)*64);
      __syncthreads(); kitgates(gn, 128+(2*k2)*64); if (kc<16) kitf1(fa, (2*k2)*64);
      __syncthreads(); sth(rb); if (2*k2+2<8) ldh(ra, hn, (2*k2+2)*64);
      __syncthreads(); kitgates(gn, 128+(2*k2+1)*64); if (kc<16) kitf1(fa, (2*k2+1)*64);
    }
    #pragma unroll
    for (int i=0;i<2;i++)
      #pragma unroll
      for (int g=0;g<4;g++) gach[i][g]=gn[i][g];
    if (kc<16){
      #pragma unroll
      for (int i=0;i<2;i++)
        #pragma unroll
        for (int r=0;r<4;r++){
          int m=w*32+i*16+(lane>>4)*4+r;
          Hs[m*16+lr]=f2b(fmaxf(fa[i][r]+b1,0.f));
        }
      __syncthreads();
      #pragma unroll
      for (int q=0;q<2;q++){
        int cc=tid*2+q, sm=cc>>2, pt=cc&3;
        ast8(P.hmid + (size_t)(bt*128+sm)*256 + kc*16 + pt*4, *(const u64*)(Hs + sm*16 + pt*4));
      }
      arrive(flags, kc, 3u*t+2u);
    } else if (kc<24){
      // ---- FFN2: pose_{t+1} = hmid @ W2d_slice^T + b2d ----
      waitflags(flags, 0, 16, 3u*t+2u);
      f32x4 fa2[2]; fa2[0]=(f32x4){0.f,0.f,0.f,0.f}; fa2[1]=fa2[0];
      for (int kit=0;kit<4;kit++){
        __syncthreads(); ldst8(P.hmid, 256, kit*64); __syncthreads(); kitf2(fa2, kit*64);
      }
      int pc=(kc-16)*16+lr;
      #pragma unroll
      for (int i=0;i<2;i++)
        #pragma unroll
        for (int r=0;r<4;r++){
          int m=w*32+i*16+(lane>>4)*4+r;
          float v=fa2[i][r]+b2;
          Hs[m*16+lr]=f2b(v);
          P.outd[(size_t)(bt*128+m)*32768 + (size_t)t*128 + pc]=v;
        }
      __syncthreads();
      #pragma unroll
      for (int q=0;q<2;q++){
        int cc=tid*2+q, sm=cc>>2, pt=cc&3;
        ast8(P.pose + (size_t)(bt*128+sm)*128 + (kc-16)*16 + pt*4, *(const u64*)(Hs + sm*16 + pt*4));
      }
      arrive(flags, kc, 3u*t+3u);
    }
  }
}

__global__ __launch_bounds__(512) void len_cast(const int* __restrict__ lens, float* __restrict__ out){
  int i = threadIdx.x;
  if (i < 512) out[i] = (float)lens[i];
}

// ============================== host ==============================
extern "C" void kernel_launch(void* const* d_in, const int* in_sizes, int n_in,
                              void* d_out, int out_size, void* d_ws, size_t ws_size,
                              hipStream_t stream){
  (void)in_sizes; (void)n_in; (void)out_size; (void)ws_size;
  const float* x      = (const float*)d_in[0];
  const int*   lens   = (const int*)d_in[1];
  const float* ng     = (const float*)d_in[2];
  const float* nb     = (const float*)d_in[3];
  const float* We     = (const float*)d_in[4];
  const float* be     = (const float*)d_in[5];
  const float* Wih_f  = (const float*)d_in[6];
  const float* Whh_f  = (const float*)d_in[7];
  const float* bih_f  = (const float*)d_in[8];
  const float* bhh_f  = (const float*)d_in[9];
  const float* Wih_b  = (const float*)d_in[10];
  const float* Whh_b  = (const float*)d_in[11];
  const float* bih_b  = (const float*)d_in[12];
  const float* bhh_b  = (const float*)d_in[13];
  const float* W1e    = (const float*)d_in[14];
  const float* b1e    = (const float*)d_in[15];
  const float* W2e    = (const float*)d_in[16];
  const float* b2e    = (const float*)d_in[17];
  const float* Wd     = (const float*)d_in[18];
  const float* bd     = (const float*)d_in[19];
  const float* Wp1    = (const float*)d_in[20];
  const float* bp1    = (const float*)d_in[21];
  const float* Wp2    = (const float*)d_in[22];
  const float* bp2    = (const float*)d_in[23];
  const float* Wih_d  = (const float*)d_in[24];
  const float* Whh_d  = (const float*)d_in[25];
  const float* bih_d  = (const float*)d_in[26];
  const float* bhh_d  = (const float*)d_in[27];
  const float* W1d    = (const float*)d_in[28];
  const float* b1d    = (const float*)d_in[29];
  const float* W2d    = (const float*)d_in[30];
  const float* b2d    = (const float*)d_in[31];

  char* p = (char*)d_ws;
  auto carve = [&](size_t bytes)->void*{ void* r=(void*)p; p += (bytes+255)&~(size_t)255; return r; };
  float* mu   = (float*)carve(512*4);
  float* rstd = (float*)carve(512*4);
  u16* xe     = (u16*)carve((size_t)33554432*2);
  u16* wWe  = (u16*)carve(32768*2);
  u16* wIhf = (u16*)carve(524288*2);
  u16* wHhf = (u16*)carve(1048576*2);
  u16* wIhb = (u16*)carve(524288*2);
  u16* wHhb = (u16*)carve(1048576*2);
  u16* wW1e = (u16*)carve(524288*2);
  u16* wW2e = (u16*)carve(131072*2);
  u16* wWd  = (u16*)carve(65536*2);
  u16* wWp1 = (u16*)carve(65536*2);
  u16* wWp2 = (u16*)carve(32768*2);
  u16* wIhd = (u16*)carve(786432*2);
  u16* wHhd = (u16*)carve(1048576*2);
  u16* wW1d = (u16*)carve(131072*2);
  u16* wW2d = (u16*)carve(32768*2);
  u16* hf0  = (u16*)carve(524288);
  u16* hf1  = (u16*)carve(524288);
  u16* hb0  = (u16*)carve(524288);
  u16* hb1  = (u16*)carve(524288);
  u16* hd0  = (u16*)carve(524288);
  u16* hd1  = (u16*)carve(524288);
  u16* pooled = (u16*)carve(1048576);
  u16* out1   = (u16*)carve(524288);
  u16* zlat   = (u16*)carve(262144);
  u16* x0     = (u16*)carve(262144);
  u16* t0     = (u16*)carve(262144);
  float* gix  = (float*)carve(4194304);
  u16* pose   = (u16*)carve(131072);
  u16* hmid   = (u16*)carve(262144);
  unsigned* barflags = (unsigned*)carve(12*1024*4);   // enc 8 groups + dec 4 groups, 32 flags x 128B

  float* out_x   = (float*)d_out;
  float* out_dec = out_x + 16777216;
  float* out_len = out_x + 33554432;

  hipMemcpyAsync(out_x, x, (size_t)16777216*4, hipMemcpyDeviceToDevice, stream);
  hipMemsetAsync(hf0,0,524288,stream);
  hipMemsetAsync(hb0,0,524288,stream);
  hipMemsetAsync(barflags,0,12*1024*4,stream);

  CvtJobs J;
  const float* srcs[14] = {We,Wih_f,Whh_f,Wih_b,Whh_b,W1e,W2e,Wd,Wp1,Wp2,Wih_d,Whh_d,W1d,W2d};
  u16* dsts[14] = {wWe,wIhf,wHhf,wIhb,wHhb,wW1e,wW2e,wWd,wWp1,wWp2,wIhd,wHhd,wW1d,wW2d};
  int ns[14] = {32768,524288,1048576,524288,1048576,524288,131072,65536,65536,32768,786432,1048576,131072,32768};
  int blk=0;
  for (int i=0;i<14;i++){ J.s[i]=srcs[i]; J.d[i]=dsts[i]; J.start[i]=blk; blk += ns[i]/2048; }
  cvt_w<<<blk,256,0,stream>>>(J);

  ln_stats<<<512,256,0,stream>>>(x,mu,rstd);
  ln_gemm<<<dim3(2,1024),256,0,stream>>>(x,mu,rstd,ng,nb,wWe,be,xe);

  EncP EP = {xe,lens,wIhf,wHhf,wIhb,wHhb,bih_f,bhh_f,bih_b,bhh_b,hf0,hf1,hb0,hb1,pooled,barflags};
  {
    void* ea[] = {&EP};
    if (hipLaunchCooperativeKernel((void*)enc_persist, dim3(256), dim3(256), ea, 0, stream) != hipSuccess)
      enc_persist<<<256,256,0,stream>>>(EP);
  }

  gemm_bt<64,64,true ,false><<<dim3(8,8),256,0,stream>>>(pooled,1024,wW1e,1024,b1e,nullptr,out1,nullptr,512,1024);
  gemm_bt<64,64,false,false><<<dim3(4,8),256,0,stream>>>(out1,512,wW2e,512,b2e,nullptr,zlat,nullptr,256,512);
  gemm_bt<64,64,true ,false><<<dim3(4,8),256,0,stream>>>(zlat,256,wWd,256,bd,nullptr,x0,nullptr,256,256);
  gemm_bt<64,64,true ,false><<<dim3(4,8),256,0,stream>>>(x0,256,wWp1,256,bp1,nullptr,t0,nullptr,256,256);
  gemm_bt<64,64,false,false><<<dim3(2,8),256,0,stream>>>(t0,256,wWp2,256,bp2,nullptr,pose,nullptr,128,256);
  gemm_bt<64,128,false,true><<<dim3(16,8),256,0,stream>>>(x0,256,wIhd,384,bih_d,bhh_d,nullptr,gix,2048,256);

  DecP DP = {wIhd,wHhd,gix,wW1d,b1d,wW2d,b2d,hd0,hd1,pose,hmid,out_dec,barflags + 8*1024};
  {
    void* da[] = {&DP};
    if (hipLaunchCooperativeKernel((void*)dec_persist, dim3(128), dim3(256), da, 0, stream) != hipSuccess)
      dec_persist<<<128,256,0,stream>>>(DP);
  }

  len_cast<<<1,512,0,stream>>>(lens,out_len);
}

// Round 5
// 9961.248 us; speedup vs baseline: 2.7196x; 1.0492x over previous
//
#include <hip/hip_runtime.h>
#include <stdint.h>
#include <math.h>

typedef unsigned short u16;
typedef unsigned long long u64;
typedef short s16x8 __attribute__((ext_vector_type(8)));
typedef __bf16 bv8 __attribute__((ext_vector_type(8)));
typedef float f32x4 __attribute__((ext_vector_type(4)));

#define DEV static __device__ __forceinline__

DEV float b2f(u16 x){ union{unsigned u; float f;} v; v.u=((unsigned)x)<<16; return v.f; }
DEV u16 f2b(float f){ union{float f; unsigned u;} v; v.f=f; unsigned u=v.u; u += 0x7fff + ((u>>16)&1u); return (u16)(u>>16); }
DEV float sigm(float x){ return 1.f/(1.f+__expf(-x)); }
DEV float tanh_(float x){ float cx=fminf(fmaxf(x,-20.f),20.f); float e=__expf(2.f*cx); return (e-1.f)/(e+1.f); }
DEV f32x4 mfma16(bv8 a, bv8 b, f32x4 c){ return __builtin_amdgcn_mfma_f32_16x16x32_bf16(a,b,c,0,0,0); }
DEV bv8 ldf(const u16* p){ return __builtin_bit_cast(bv8, *(const s16x8*)p); }

// ---- coherence-light cross-block primitives: all shared state via sc1 (L3), never L2 ----
DEV u64 ald8(const void* p){ return __hip_atomic_load((const u64*)p, __ATOMIC_RELAXED, __HIP_MEMORY_SCOPE_AGENT); }
DEV void ast8(void* p, u64 v){ __hip_atomic_store((u64*)p, v, __ATOMIC_RELAXED, __HIP_MEMORY_SCOPE_AGENT); }
DEV unsigned ald4(const unsigned* p){ return __hip_atomic_load(p, __ATOMIC_RELAXED, __HIP_MEMORY_SCOPE_AGENT); }

// relaxed flag store; ordering provided by explicit vmcnt(0) drain + block sync.
// (a RELEASE store at agent scope would emit an L2 writeback on gfx950 — measured 17-23us/step in r4)
DEV void arrive(unsigned* flags, int my, unsigned e){
  asm volatile("s_waitcnt vmcnt(0)" ::: "memory");   // this thread's sc1 stores reached L3
  __syncthreads();                                    // => all threads' stores reached L3
  if (threadIdx.x==0)
    __hip_atomic_store(&flags[my*32], e, __ATOMIC_RELAXED, __HIP_MEMORY_SCOPE_AGENT);
}
DEV void waitflags(unsigned* flags, int lo, int n, unsigned e){
  int t = (int)threadIdx.x;
  if (t>=lo && t<lo+n){
    while (ald4(&flags[t*32]) < e) __builtin_amdgcn_s_sleep(1);
  }
  __syncthreads();
}

// ---------------- weight f32 -> bf16 conversion ----------------
struct CvtJobs { const float* s[14]; u16* d[14]; int start[14]; };

__global__ __launch_bounds__(256) void cvt_w(CvtJobs J){
  int blk = blockIdx.x, tid = threadIdx.x;
  int j = 0;
  #pragma unroll
  for (int k=1;k<14;k++) if (blk >= J.start[k]) j = k;
  size_t idx = (size_t)(blk - J.start[j])*2048 + (size_t)tid*8;
  const f32x4* ps = (const f32x4*)(J.s[j] + idx);
  f32x4 a = ps[0], b = ps[1];
  s16x8 o;
  #pragma unroll
  for (int i=0;i<4;i++){ o[i]=(short)f2b(a[i]); o[4+i]=(short)f2b(b[i]); }
  *(s16x8*)(J.d[j] + idx) = o;
}

// ---------------- LayerNorm stats ----------------
__global__ __launch_bounds__(256) void ln_stats(const float* __restrict__ x,
                                                float* __restrict__ mu, float* __restrict__ rstd){
  int b = blockIdx.x;
  const float* xb = x + (size_t)b*32768;
  float s1=0.f, s2=0.f;
  for (int i = threadIdx.x*4; i < 32768; i += 256*4){
    f32x4 v = *(const f32x4*)(xb+i);
    #pragma unroll
    for (int j=0;j<4;j++){ float f = v[j]; s1+=f; s2+=f*f; }
  }
  #pragma unroll
  for (int o=32;o>0;o>>=1){ s1 += __shfl_down(s1,o); s2 += __shfl_down(s2,o); }
  __shared__ float r1[4], r2[4];
  int w = threadIdx.x>>6;
  if ((threadIdx.x&63)==0){ r1[w]=s1; r2[w]=s2; }
  __syncthreads();
  if (threadIdx.x==0){
    float a=0.f,c=0.f;
    for (int i=0;i<4;i++){ a+=r1[i]; c+=r2[i]; }
    float m=a/32768.f, v=c/32768.f-m*m;
    mu[b]=m; rstd[b]=1.f/sqrtf(v+1e-5f);
  }
}

// ---------------- fused LN + encode GEMM ----------------
__global__ __launch_bounds__(256) void ln_gemm(const float* __restrict__ x,
    const float* __restrict__ mu, const float* __restrict__ rstd,
    const float* __restrict__ g, const float* __restrict__ bn,
    const u16* __restrict__ Wb, const float* __restrict__ be, u16* __restrict__ xe){
  __shared__ __align__(16) u16 As[128*32];
  __shared__ __align__(16) u16 Ws[128*32];
  int tid=threadIdx.x, lane=tid&63, wid=tid>>6;
  int wr=wid>>1, wc=wid&1;
  long m0=(long)blockIdx.y*128, n0=(long)blockIdx.x*128;
  int lr=lane&15, lk=(lane>>4)*8;
  f32x4 acc[4][4];
  #pragma unroll
  for (int i=0;i<4;i++)
    #pragma unroll
    for (int j=0;j<4;j++) acc[i][j]=(f32x4){0.f,0.f,0.f,0.f};

  for (int k0=0;k0<128;k0+=32){
    __syncthreads();
    #pragma unroll
    for (int c=tid;c<512;c+=256){
      int row=c>>2, kb=(c&3)*8;
      long R=m0+row;
      int b=(int)(R>>8), tt=(int)(R&255);
      float m=mu[b], rs=rstd[b];
      const f32x4* px=(const f32x4*)(x + R*128 + k0+kb);
      const f32x4* pg=(const f32x4*)(g + tt*128 + k0+kb);
      const f32x4* pb=(const f32x4*)(bn + tt*128 + k0+kb);
      f32x4 x0=px[0], x1=px[1], g0=pg[0], g1=pg[1], b0=pb[0], b1=pb[1];
      s16x8 o;
      #pragma unroll
      for (int j=0;j<4;j++){
        o[j]   = (short)f2b((x0[j]-m)*rs*g0[j] + b0[j]);
        o[4+j] = (short)f2b((x1[j]-m)*rs*g1[j] + b1[j]);
      }
      *(s16x8*)(As + row*32 + kb) = o;
    }
    #pragma unroll
    for (int c=tid;c<512;c+=256){
      int row=c>>2, kb=(c&3)*8;
      *(s16x8*)(Ws + row*32 + kb) = *(const s16x8*)(Wb + (n0+row)*128 + k0+kb);
    }
    __syncthreads();
    bv8 af[4], bf[4];
    #pragma unroll
    for (int i=0;i<4;i++) af[i] = ldf(As + (wr*64+i*16+lr)*32 + lk);
    #pragma unroll
    for (int j=0;j<4;j++) bf[j] = ldf(Ws + (wc*64+j*16+lr)*32 + lk);
    #pragma unroll
    for (int i=0;i<4;i++)
      #pragma unroll
      for (int j=0;j<4;j++) acc[i][j] = mfma16(af[i], bf[j], acc[i][j]);
  }
  #pragma unroll
  for (int i=0;i<4;i++)
    #pragma unroll
    for (int j=0;j<4;j++)
      #pragma unroll
      for (int r=0;r<4;r++){
        int m = wr*64+i*16+(lane>>4)*4+r;
        int n = wc*64+j*16+lr;
        float v = acc[i][j][r] + be[n0+n];
        xe[(m0+m)*256 + n0+n] = f2b(fmaxf(v,0.f));
      }
}

// ---------------- generic GEMM ----------------
template<int BM, int BN, bool RELU, bool OUTF32>
__global__ __launch_bounds__(256) void gemm_bt(const u16* __restrict__ A, int lda,
                                               const u16* __restrict__ W, int ldw,
                                               const float* __restrict__ bias1, const float* __restrict__ bias2,
                                               u16* __restrict__ Cb, float* __restrict__ Cf, int ldc, int K){
  constexpr int BK=32;
  constexpr int FM=BM/32, FN=BN/32;
  __shared__ __align__(16) u16 As[BM*BK];
  __shared__ __align__(16) u16 Ws[BN*BK];
  int tid=threadIdx.x, lane=tid&63, wid=tid>>6;
  int wr=wid>>1, wc=wid&1;
  long m0=(long)blockIdx.y*BM, n0=(long)blockIdx.x*BN;
  int lr=lane&15, lk=(lane>>4)*8;
  f32x4 acc[FM][FN];
  #pragma unroll
  for (int i=0;i<FM;i++)
    #pragma unroll
    for (int j=0;j<FN;j++) acc[i][j] = (f32x4){0.f,0.f,0.f,0.f};
  for (int k0=0;k0<K;k0+=BK){
    __syncthreads();
    #pragma unroll
    for (int c=tid;c<BM*4;c+=256){
      int row=c>>2, kb=(c&3)*8;
      *(s16x8*)(As + row*BK + kb) = *(const s16x8*)(A + (m0+row)*lda + k0+kb);
    }
    #pragma unroll
    for (int c=tid;c<BN*4;c+=256){
      int row=c>>2, kb=(c&3)*8;
      *(s16x8*)(Ws + row*BK + kb) = *(const s16x8*)(W + (n0+row)*ldw + k0+kb);
    }
    __syncthreads();
    bv8 af[FM], bf[FN];
    #pragma unroll
    for (int i=0;i<FM;i++) af[i] = ldf(As + (wr*(BM/2)+i*16+lr)*BK + lk);
    #pragma unroll
    for (int j=0;j<FN;j++) bf[j] = ldf(Ws + (wc*(BN/2)+j*16+lr)*BK + lk);
    #pragma unroll
    for (int i=0;i<FM;i++)
      #pragma unroll
      for (int j=0;j<FN;j++) acc[i][j] = mfma16(af[i], bf[j], acc[i][j]);
  }
  #pragma unroll
  for (int i=0;i<FM;i++)
    #pragma unroll
    for (int j=0;j<FN;j++)
      #pragma unroll
      for (int r=0;r<4;r++){
        int m = wr*(BM/2)+i*16+(lane>>4)*4+r;
        int n = wc*(BN/2)+j*16+lr;
        float v = acc[i][j][r];
        if (bias1) v += bias1[n0+n];
        if (bias2) v += bias2[n0+n];
        if (RELU) v = fmaxf(v,0.f);
        if (OUTF32) Cf[(m0+m)*ldc + n0+n] = v;
        else        Cb[(m0+m)*ldc + n0+n] = f2b(v);
      }
}

// ================= persistent encoder =================
// grid 256: grp = bx&7 (dir*4+bt), kc = bx>>3 (16 cells)
struct EncP {
  const u16* xe; const int* lens;
  const u16 *Wihf,*Whhf,*Wihb,*Whhb;
  const float *bif,*bhf,*bib,*bhb;
  u16 *hf0,*hf1,*hb0,*hb1,*pooled;
  unsigned* flags;
};

__global__ __launch_bounds__(256,1) void enc_persist(EncP P){
  __shared__ __align__(16) u16 Wl[64*776];
  __shared__ __align__(16) u16 As[2*128*72];
  __shared__ __align__(16) u16 Hs[128*16];
  const int tid=threadIdx.x, lane=tid&63, w=tid>>6;
  const int bx=blockIdx.x;
  const int grp=bx&7, kc=bx>>3;
  const int dir=grp>>2, bt=grp&3;
  const int lr=lane&15, lk=(lane>>4)*8;
  unsigned* flags = P.flags + grp*1024;
  const u16* Wih = dir? P.Wihb : P.Wihf;
  const u16* Whh = dir? P.Whhb : P.Whhf;
  const float* bi = dir? P.bib : P.bif;
  const float* bh = dir? P.bhb : P.bhf;
  u16* h0 = dir? P.hb0 : P.hf0;
  u16* h1 = dir? P.hb1 : P.hf1;

  for (int idx=tid; idx<64*96; idx+=256){
    int row=idx/96, col=(idx%96)*8;
    int g=row>>4, c=row&15;
    size_t grow=(size_t)(g*512 + kc*16 + c);
    const u16* src = (col<256)? (Wih + grow*256 + col) : (Whh + grow*512 + (col-256));
    *(s16x8*)(Wl + row*776 + col) = *(const s16x8*)src;
  }
  const int cg = kc*16 + lr;
  const float b_i=bi[cg]+bh[cg], b_f=bi[512+cg]+bh[512+cg];
  const float b_g=bi[1024+cg]+bh[1024+cg], b_o=bi[1536+cg]+bh[1536+cg];
  const int row_s=tid>>1, c0s=(tid&1)*32;
  const int slen = P.lens[bt*128+row_s];
  const size_t arow=(size_t)(bt*128+row_s);
  int elen[2][4]; float cs[2][4], hh[2][4], asum[2][4];
  #pragma unroll
  for (int i=0;i<2;i++)
    #pragma unroll
    for (int r=0;r<4;r++){
      int m=w*32+i*16+(lane>>4)*4+r;
      elen[i][r]=P.lens[bt*128+m];
      cs[i][r]=0.f; hh[i][r]=0.f; asum[i][r]=0.f;
    }

  auto sth2 = [&](int b, const u64* r){
    u16* dst = As + b*9216 + row_s*72 + c0s;
    #pragma unroll
    for (int j=0;j<8;j++) *(u64*)(dst + j*4) = r[j];
  };
  auto kit = [&](f32x4 (&acc)[2][4], int b, int wcol){
    const u16* base = As + b*9216;
    #pragma unroll
    for (int kk=0;kk<2;kk++){
      bv8 a0=ldf(base+(w*32+lr)*72+kk*32+lk);
      bv8 a1=ldf(base+(w*32+16+lr)*72+kk*32+lk);
      #pragma unroll
      for (int g=0;g<4;g++){
        bv8 bf=ldf(Wl+(g*16+lr)*776 + wcol + kk*32+lk);
        acc[0][g]=mfma16(a0,bf,acc[0][g]);
        acc[1][g]=mfma16(a1,bf,acc[1][g]);
      }
    }
  };
  // x-part: plain cached loads, full prefetch, 4 kits
  auto xpart = [&](int tt, f32x4 (&xacc)[2][4]){
    u64 px[4][8];
    const u16* xr = P.xe + (arow*256 + (size_t)tt)*256 + c0s;
    #pragma unroll
    for (int k=0;k<4;k++)
      #pragma unroll
      for (int j=0;j<8;j++) px[k][j] = *(const u64*)(xr + k*64 + j*4);
    sth2(0, px[0]);
    #pragma unroll
    for (int k=0;k<4;k++){
      __syncthreads();
      if (k<3) sth2((k+1)&1, px[k+1]);
      kit(xacc, k&1, k*64);
    }
  };

  __syncthreads();   // weights staged
  f32x4 xacc[2][4];
  #pragma unroll
  for (int i=0;i<2;i++)
    #pragma unroll
    for (int g=0;g<4;g++) xacc[i][g]=(f32x4){0.f,0.f,0.f,0.f};
  xpart(dir? (slen-1) : 0, xacc);

  for (int t=0;t<256;t++){
    const u16* hp = (t&1)? h1 : h0;
    u16*       hn = (t&1)? h0 : h1;
    waitflags(flags, 0, 32, (unsigned)t);
    f32x4 acc[2][4];
    #pragma unroll
    for (int i=0;i<2;i++)
      #pragma unroll
      for (int g=0;g<4;g++) acc[i][g]=xacc[i][g];
    // h-part: prefetch ALL K=512 into regs (64 x 8B sc1 loads), then 1-sync-per-kit drain
    u64 pf[8][8];
    {
      const u16* hr = hp + arow*512 + c0s;
      #pragma unroll
      for (int k=0;k<8;k++)
        #pragma unroll
        for (int j=0;j<8;j++) pf[k][j] = ald8(hr + k*64 + j*4);
    }
    sth2(0, pf[0]);
    #pragma unroll
    for (int k=0;k<8;k++){
      __syncthreads();
      if (k<7) sth2((k+1)&1, pf[k+1]);
      kit(acc, k&1, 256+k*64);
    }
    #pragma unroll
    for (int i=0;i<2;i++)
      #pragma unroll
      for (int r=0;r<4;r++){
        int m=w*32+i*16+(lane>>4)*4+r;
        if (t<elen[i][r]){
          float iv=sigm(acc[i][0][r]+b_i), fv=sigm(acc[i][1][r]+b_f);
          float gv=tanh_(acc[i][2][r]+b_g), ov=sigm(acc[i][3][r]+b_o);
          float c2=fv*cs[i][r]+iv*gv, h2v=ov*tanh_(c2);
          cs[i][r]=c2; hh[i][r]=h2v; asum[i][r]+=h2v;
        }
        Hs[m*16+lr]=f2b(hh[i][r]);
      }
    __syncthreads();
    #pragma unroll
    for (int q=0;q<2;q++){
      int cc=tid*2+q, sm=cc>>2, pt=cc&3;
      ast8(hn + (size_t)(bt*128+sm)*512 + kc*16 + pt*4, *(const u64*)(Hs + sm*16 + pt*4));
    }
    arrive(flags, kc, (unsigned)(t+1));
    // overlap window: x-part gates for t+1
    #pragma unroll
    for (int i=0;i<2;i++)
      #pragma unroll
      for (int g=0;g<4;g++) xacc[i][g]=(f32x4){0.f,0.f,0.f,0.f};
    if (t<255){
      int tp=t+1;
      xpart(dir? max(slen-1-tp,0) : tp, xacc);
    }
  }
  #pragma unroll
  for (int i=0;i<2;i++)
    #pragma unroll
    for (int r=0;r<4;r++){
      int m=w*32+i*16+(lane>>4)*4+r;
      P.pooled[(size_t)(bt*128+m)*1024 + (size_t)dir*512 + cg]=f2b(asum[i][r]/(float)elen[i][r]);
    }
}

// ================= persistent decoder =================
// grid 128: bt = bx&3, kc = bx>>2 (16 cells)
struct DecP {
  const u16 *Wihd,*Whhd; const float* gix;
  const u16* W1d; const float* b1d;
  const u16* W2d; const float* b2d;
  u16 *h0,*h1,*pose,*hmid;
  float* outd;
  unsigned* flags;
};

__global__ __launch_bounds__(256,1) void dec_persist(DecP P){
  __shared__ __align__(16) u16 Wl[64*648];
  __shared__ __align__(16) u16 As[2*128*72];
  __shared__ __align__(16) u16 F1[16*520];
  __shared__ __align__(16) u16 F2[16*264];
  __shared__ __align__(16) u16 Hs[128*16];
  const int tid=threadIdx.x, lane=tid&63, w=tid>>6;
  const int bx=blockIdx.x;
  const int bt=bx&3, kc=bx>>2;
  const int lr=lane&15, lk=(lane>>4)*8;
  unsigned* flags = P.flags + bt*1024;

  for (int idx=tid; idx<64*80; idx+=256){
    int row=idx/80, col=(idx%80)*8;
    int g=row>>4, c=row&15;
    size_t grow=(size_t)(g*512 + kc*16 + c);
    const u16* src = (col<128)? (P.Wihd + grow*384 + 256 + col) : (P.Whhd + grow*512 + (col-128));
    *(s16x8*)(Wl + row*648 + col) = *(const s16x8*)src;
  }
  if (kc<16){
    for (int idx=tid; idx<16*64; idx+=256){
      int rr=idx>>6, col=(idx&63)*8;
      *(s16x8*)(F1 + rr*520 + col) = *(const s16x8*)(P.W1d + (size_t)(kc*16+rr)*512 + col);
    }
  } else if (kc<24){
    for (int idx=tid; idx<16*32; idx+=256){
      int rr=idx>>5, col=(idx&31)*8;
      *(s16x8*)(F2 + rr*264 + col) = *(const s16x8*)(P.W2d + (size_t)((kc-16)*16+rr)*256 + col);
    }
  }
  float gx[2][4][4];
  #pragma unroll
  for (int i=0;i<2;i++)
    #pragma unroll
    for (int g=0;g<4;g++)
      #pragma unroll
      for (int r=0;r<4;r++){
        int m=w*32+i*16+(lane>>4)*4+r;
        gx[i][g][r]=P.gix[(size_t)(bt*128+m)*2048 + (size_t)g*512 + kc*16 + lr];
      }
  const float b1=(kc<16)? P.b1d[kc*16+lr] : 0.f;
  const float b2=(kc>=16&&kc<24)? P.b2d[(kc-16)*16+lr] : 0.f;
  const int row_s=tid>>1, c0s=(tid&1)*32;
  const size_t arow=(size_t)(bt*128+row_s);
  float cs[2][4];
  f32x4 gach[2][4];
  #pragma unroll
  for (int i=0;i<2;i++){
    #pragma unroll
    for (int r=0;r<4;r++) cs[i][r]=0.f;
    #pragma unroll
    for (int g=0;g<4;g++) gach[i][g]=(f32x4){0.f,0.f,0.f,0.f};
  }

  auto sth2 = [&](int b, const u64* r){
    u16* dst = As + b*9216 + row_s*72 + c0s;
    #pragma unroll
    for (int j=0;j<8;j++) *(u64*)(dst + j*4) = r[j];
  };
  auto lda2 = [&](bv8& a0, bv8& a1, int b, int kk){
    const u16* base = As + b*9216;
    a0=ldf(base+(w*32+lr)*72+kk*32+lk);
    a1=ldf(base+(w*32+16+lr)*72+kk*32+lk);
  };
  auto kitg = [&](f32x4 (&acc)[2][4], int b, int wcol){
    #pragma unroll
    for (int kk=0;kk<2;kk++){
      bv8 a0,a1; lda2(a0,a1,b,kk);
      #pragma unroll
      for (int g=0;g<4;g++){
        bv8 bf=ldf(Wl+(g*16+lr)*648 + wcol + kk*32+lk);
        acc[0][g]=mfma16(a0,bf,acc[0][g]);
        acc[1][g]=mfma16(a1,bf,acc[1][g]);
      }
    }
  };
  auto kitf1 = [&](f32x4 (&fa)[2], int b, int fcol){
    #pragma unroll
    for (int kk=0;kk<2;kk++){
      bv8 a0,a1; lda2(a0,a1,b,kk);
      bv8 bf=ldf(F1 + lr*520 + fcol + kk*32+lk);
      fa[0]=mfma16(a0,bf,fa[0]); fa[1]=mfma16(a1,bf,fa[1]);
    }
  };
  auto kitf2 = [&](f32x4 (&fa)[2], int b, int fcol){
    #pragma unroll
    for (int kk=0;kk<2;kk++){
      bv8 a0,a1; lda2(a0,a1,b,kk);
      bv8 bf=ldf(F2 + lr*264 + fcol + kk*32+lk);
      fa[0]=mfma16(a0,bf,fa[0]); fa[1]=mfma16(a1,bf,fa[1]);
    }
  };

  for (int t=0;t<256;t++){
    u16* hn = (t&1)? P.h0 : P.h1;
    // wait pose_t (FFN2 blocks of step t-1)
    waitflags(flags, 16, 8, 3u*(unsigned)t);
    // ---- P1: gates = gix + gates_h(precomputed) + pose-part (K=128) ----
    f32x4 acc[2][4];
    #pragma unroll
    for (int i=0;i<2;i++)
      #pragma unroll
      for (int g=0;g<4;g++){
        f32x4 gv = (f32x4){gx[i][g][0],gx[i][g][1],gx[i][g][2],gx[i][g][3]};
        acc[i][g]=gach[i][g]+gv;
      }
    {
      u64 pp[2][8];
      const u16* pr = P.pose + arow*128 + c0s;
      #pragma unroll
      for (int k=0;k<2;k++)
        #pragma unroll
        for (int j=0;j<8;j++) pp[k][j] = ald8(pr + k*64 + j*4);
      sth2(0, pp[0]);
      __syncthreads();
      sth2(1, pp[1]);
      kitg(acc, 0, 0);
      __syncthreads();
      kitg(acc, 1, 64);
    }
    #pragma unroll
    for (int i=0;i<2;i++)
      #pragma unroll
      for (int r=0;r<4;r++){
        float iv=sigm(acc[i][0][r]), fv=sigm(acc[i][1][r]);
        float gv=tanh_(acc[i][2][r]), ov=sigm(acc[i][3][r]);
        float c2=fv*cs[i][r]+iv*gv, h2v=ov*tanh_(c2);
        cs[i][r]=c2;
        int m=w*32+i*16+(lane>>4)*4+r;
        Hs[m*16+lr]=f2b(h2v);
      }
    __syncthreads();
    #pragma unroll
    for (int q=0;q<2;q++){
      int cc=tid*2+q, sm=cc>>2, pt=cc&3;
      ast8(hn + (size_t)(bt*128+sm)*512 + kc*16 + pt*4, *(const u64*)(Hs + sm*16 + pt*4));
    }
    arrive(flags, kc, 3u*t+1u);
    waitflags(flags, 0, 32, 3u*t+1u);
    // ---- combined: gates_h for t+1 (all) + FFN1 (kc<16), K=512 over h2, full prefetch ----
    f32x4 gn[2][4]; f32x4 fa[2];
    #pragma unroll
    for (int i=0;i<2;i++)
      #pragma unroll
      for (int g=0;g<4;g++) gn[i][g]=(f32x4){0.f,0.f,0.f,0.f};
    fa[0]=(f32x4){0.f,0.f,0.f,0.f}; fa[1]=fa[0];
    {
      u64 pf[8][8];
      const u16* hr = hn + arow*512 + c0s;
      #pragma unroll
      for (int k=0;k<8;k++)
        #pragma unroll
        for (int j=0;j<8;j++) pf[k][j] = ald8(hr + k*64 + j*4);
      sth2(0, pf[0]);
      #pragma unroll
      for (int k=0;k<8;k++){
        __syncthreads();
        if (k<7) sth2((k+1)&1, pf[k+1]);
        kitg(gn, k&1, 128+k*64);
        if (kc<16) kitf1(fa, k&1, k*64);
      }
    }
    #pragma unroll
    for (int i=0;i<2;i++)
      #pragma unroll
      for (int g=0;g<4;g++) gach[i][g]=gn[i][g];
    if (kc<16){
      #pragma unroll
      for (int i=0;i<2;i++)
        #pragma unroll
        for (int r=0;r<4;r++){
          int m=w*32+i*16+(lane>>4)*4+r;
          Hs[m*16+lr]=f2b(fmaxf(fa[i][r]+b1,0.f));
        }
      __syncthreads();
      #pragma unroll
      for (int q=0;q<2;q++){
        int cc=tid*2+q, sm=cc>>2, pt=cc&3;
        ast8(P.hmid + (size_t)(bt*128+sm)*256 + kc*16 + pt*4, *(const u64*)(Hs + sm*16 + pt*4));
      }
      arrive(flags, kc, 3u*t+2u);
    } else if (kc<24){
      // ---- FFN2: pose_{t+1} = hmid @ W2d_slice^T + b2d ----
      waitflags(flags, 0, 16, 3u*t+2u);
      f32x4 fa2[2]; fa2[0]=(f32x4){0.f,0.f,0.f,0.f}; fa2[1]=fa2[0];
      {
        u64 pm[4][8];
        const u16* mr = P.hmid + arow*256 + c0s;
        #pragma unroll
        for (int k=0;k<4;k++)
          #pragma unroll
          for (int j=0;j<8;j++) pm[k][j] = ald8(mr + k*64 + j*4);
        sth2(0, pm[0]);
        #pragma unroll
        for (int k=0;k<4;k++){
          __syncthreads();
          if (k<3) sth2((k+1)&1, pm[k+1]);
          kitf2(fa2, k&1, k*64);
        }
      }
      int pc=(kc-16)*16+lr;
      #pragma unroll
      for (int i=0;i<2;i++)
        #pragma unroll
        for (int r=0;r<4;r++){
          int m=w*32+i*16+(lane>>4)*4+r;
          float v=fa2[i][r]+b2;
          Hs[m*16+lr]=f2b(v);
          P.outd[(size_t)(bt*128+m)*32768 + (size_t)t*128 + pc]=v;
        }
      __syncthreads();
      #pragma unroll
      for (int q=0;q<2;q++){
        int cc=tid*2+q, sm=cc>>2, pt=cc&3;
        ast8(P.pose + (size_t)(bt*128+sm)*128 + (kc-16)*16 + pt*4, *(const u64*)(Hs + sm*16 + pt*4));
      }
      arrive(flags, kc, 3u*t+3u);
    }
  }
}

__global__ __launch_bounds__(512) void len_cast(const int* __restrict__ lens, float* __restrict__ out){
  int i = threadIdx.x;
  if (i < 512) out[i] = (float)lens[i];
}

// ============================== host ==============================
extern "C" void kernel_launch(void* const* d_in, const int* in_sizes, int n_in,
                              void* d_out, int out_size, void* d_ws, size_t ws_size,
                              hipStream_t stream){
  (void)in_sizes; (void)n_in; (void)out_size; (void)ws_size;
  const float* x      = (const float*)d_in[0];
  const int*   lens   = (const int*)d_in[1];
  const float* ng     = (const float*)d_in[2];
  const float* nb     = (const float*)d_in[3];
  const float* We     = (const float*)d_in[4];
  const float* be     = (const float*)d_in[5];
  const float* Wih_f  = (const float*)d_in[6];
  const float* Whh_f  = (const float*)d_in[7];
  const float* bih_f  = (const float*)d_in[8];
  const float* bhh_f  = (const float*)d_in[9];
  const float* Wih_b  = (const float*)d_in[10];
  const float* Whh_b  = (const float*)d_in[11];
  const float* bih_b  = (const float*)d_in[12];
  const float* bhh_b  = (const float*)d_in[13];
  const float* W1e    = (const float*)d_in[14];
  const float* b1e    = (const float*)d_in[15];
  const float* W2e    = (const float*)d_in[16];
  const float* b2e    = (const float*)d_in[17];
  const float* Wd     = (const float*)d_in[18];
  const float* bd     = (const float*)d_in[19];
  const float* Wp1    = (const float*)d_in[20];
  const float* bp1    = (const float*)d_in[21];
  const float* Wp2    = (const float*)d_in[22];
  const float* bp2    = (const float*)d_in[23];
  const float* Wih_d  = (const float*)d_in[24];
  const float* Whh_d  = (const float*)d_in[25];
  const float* bih_d  = (const float*)d_in[26];
  const float* bhh_d  = (const float*)d_in[27];
  const float* W1d    = (const float*)d_in[28];
  const float* b1d    = (const float*)d_in[29];
  const float* W2d    = (const float*)d_in[30];
  const float* b2d    = (const float*)d_in[31];

  char* p = (char*)d_ws;
  auto carve = [&](size_t bytes)->void*{ void* r=(void*)p; p += (bytes+255)&~(size_t)255; return r; };
  float* mu   = (float*)carve(512*4);
  float* rstd = (float*)carve(512*4);
  u16* xe     = (u16*)carve((size_t)33554432*2);
  u16* wWe  = (u16*)carve(32768*2);
  u16* wIhf = (u16*)carve(524288*2);
  u16* wHhf = (u16*)carve(1048576*2);
  u16* wIhb = (u16*)carve(524288*2);
  u16* wHhb = (u16*)carve(1048576*2);
  u16* wW1e = (u16*)carve(524288*2);
  u16* wW2e = (u16*)carve(131072*2);
  u16* wWd  = (u16*)carve(65536*2);
  u16* wWp1 = (u16*)carve(65536*2);
  u16* wWp2 = (u16*)carve(32768*2);
  u16* wIhd = (u16*)carve(786432*2);
  u16* wHhd = (u16*)carve(1048576*2);
  u16* wW1d = (u16*)carve(131072*2);
  u16* wW2d = (u16*)carve(32768*2);
  u16* hf0  = (u16*)carve(524288);
  u16* hf1  = (u16*)carve(524288);
  u16* hb0  = (u16*)carve(524288);
  u16* hb1  = (u16*)carve(524288);
  u16* hd0  = (u16*)carve(524288);
  u16* hd1  = (u16*)carve(524288);
  u16* pooled = (u16*)carve(1048576);
  u16* out1   = (u16*)carve(524288);
  u16* zlat   = (u16*)carve(262144);
  u16* x0     = (u16*)carve(262144);
  u16* t0     = (u16*)carve(262144);
  float* gix  = (float*)carve(4194304);
  u16* pose   = (u16*)carve(131072);
  u16* hmid   = (u16*)carve(262144);
  unsigned* barflags = (unsigned*)carve(12*1024*4);

  float* out_x   = (float*)d_out;
  float* out_dec = out_x + 16777216;
  float* out_len = out_x + 33554432;

  hipMemcpyAsync(out_x, x, (size_t)16777216*4, hipMemcpyDeviceToDevice, stream);
  hipMemsetAsync(hf0,0,524288,stream);
  hipMemsetAsync(hb0,0,524288,stream);
  hipMemsetAsync(barflags,0,12*1024*4,stream);

  CvtJobs J;
  const float* srcs[14] = {We,Wih_f,Whh_f,Wih_b,Whh_b,W1e,W2e,Wd,Wp1,Wp2,Wih_d,Whh_d,W1d,W2d};
  u16* dsts[14] = {wWe,wIhf,wHhf,wIhb,wHhb,wW1e,wW2e,wWd,wWp1,wWp2,wIhd,wHhd,wW1d,wW2d};
  int ns[14] = {32768,524288,1048576,524288,1048576,524288,131072,65536,65536,32768,786432,1048576,131072,32768};
  int blk=0;
  for (int i=0;i<14;i++){ J.s[i]=srcs[i]; J.d[i]=dsts[i]; J.start[i]=blk; blk += ns[i]/2048; }
  cvt_w<<<blk,256,0,stream>>>(J);

  ln_stats<<<512,256,0,stream>>>(x,mu,rstd);
  ln_gemm<<<dim3(2,1024),256,0,stream>>>(x,mu,rstd,ng,nb,wWe,be,xe);

  EncP EP = {xe,lens,wIhf,wHhf,wIhb,wHhb,bih_f,bhh_f,bih_b,bhh_b,hf0,hf1,hb0,hb1,pooled,barflags};
  {
    void* ea[] = {&EP};
    if (hipLaunchCooperativeKernel((void*)enc_persist, dim3(256), dim3(256), ea, 0, stream) != hipSuccess)
      enc_persist<<<256,256,0,stream>>>(EP);
  }

  gemm_bt<64,64,true ,false><<<dim3(8,8),256,0,stream>>>(pooled,1024,wW1e,1024,b1e,nullptr,out1,nullptr,512,1024);
  gemm_bt<64,64,false,false><<<dim3(4,8),256,0,stream>>>(out1,512,wW2e,512,b2e,nullptr,zlat,nullptr,256,512);
  gemm_bt<64,64,true ,false><<<dim3(4,8),256,0,stream>>>(zlat,256,wWd,256,bd,nullptr,x0,nullptr,256,256);
  gemm_bt<64,64,true ,false><<<dim3(4,8),256,0,stream>>>(x0,256,wWp1,256,bp1,nullptr,t0,nullptr,256,256);
  gemm_bt<64,64,false,false><<<dim3(2,8),256,0,stream>>>(t0,256,wWp2,256,bp2,nullptr,pose,nullptr,128,256);
  gemm_bt<64,128,false,true><<<dim3(16,8),256,0,stream>>>(x0,256,wIhd,384,bih_d,bhh_d,nullptr,gix,2048,256);

  DecP DP = {wIhd,wHhd,gix,wW1d,b1d,wW2d,b2d,hd0,hd1,pose,hmid,out_dec,barflags + 8*1024};
  {
    void* da[] = {&DP};
    if (hipLaunchCooperativeKernel((void*)dec_persist, dim3(128), dim3(256), da, 0, stream) != hipSuccess)
      dec_persist<<<128,256,0,stream>>>(DP);
  }

  len_cast<<<1,512,0,stream>>>(lens,out_len);
}

// Round 6
// 8841.138 us; speedup vs baseline: 3.0641x; 1.1267x over previous
//
#include <hip/hip_runtime.h>
#include <stdint.h>
#include <math.h>

typedef unsigned short u16;
typedef unsigned long long u64;
typedef short s16x8 __attribute__((ext_vector_type(8)));
typedef __bf16 bv8 __attribute__((ext_vector_type(8)));
typedef float f32x4 __attribute__((ext_vector_type(4)));

#define DEV static __device__ __forceinline__

DEV float b2f(u16 x){ union{unsigned u; float f;} v; v.u=((unsigned)x)<<16; return v.f; }
DEV u16 f2b(float f){ union{float f; unsigned u;} v; v.f=f; unsigned u=v.u; u += 0x7fff + ((u>>16)&1u); return (u16)(u>>16); }
DEV float sigm(float x){ return 1.f/(1.f+__expf(-x)); }
DEV float tanh_(float x){ float cx=fminf(fmaxf(x,-20.f),20.f); float e=__expf(2.f*cx); return (e-1.f)/(e+1.f); }
DEV f32x4 mfma16(bv8 a, bv8 b, f32x4 c){ return __builtin_amdgcn_mfma_f32_16x16x32_bf16(a,b,c,0,0,0); }
DEV bv8 ldf(const u16* p){ return __builtin_bit_cast(bv8, *(const s16x8*)p); }

DEV unsigned ald4(const unsigned* p){ return __hip_atomic_load(p, __ATOMIC_RELAXED, __HIP_MEMORY_SCOPE_AGENT); }

// once-per-hop fence pattern: plain cached state traffic; wave0 does 1 wb (release) / 1 inv (acquire).
// __syncthreads() drains all waves' stores to L2 (compiler emits vmcnt(0) before s_barrier).
DEV void arrive(unsigned* flags, int my, unsigned e){
  __syncthreads();
  if (threadIdx.x < 64){
    __builtin_amdgcn_fence(__ATOMIC_RELEASE, "agent");
    if (threadIdx.x == 0)
      __hip_atomic_store(&flags[my*32], e, __ATOMIC_RELAXED, __HIP_MEMORY_SCOPE_AGENT);
  }
}
// poll lanes must be within wave0 (index < 64)
DEV void waitflags(unsigned* flags, int lo, int n, unsigned e){
  int t = (int)threadIdx.x;
  if (t>=lo && t<lo+n){
    while (ald4(&flags[t*32]) < e) __builtin_amdgcn_s_sleep(1);
  }
  if (t < 64) __builtin_amdgcn_fence(__ATOMIC_ACQUIRE, "agent");
  __syncthreads();
}

// ---------------- weight f32 -> bf16 conversion ----------------
struct CvtJobs { const float* s[14]; u16* d[14]; int start[14]; };

__global__ __launch_bounds__(256) void cvt_w(CvtJobs J){
  int blk = blockIdx.x, tid = threadIdx.x;
  int j = 0;
  #pragma unroll
  for (int k=1;k<14;k++) if (blk >= J.start[k]) j = k;
  size_t idx = (size_t)(blk - J.start[j])*2048 + (size_t)tid*8;
  const f32x4* ps = (const f32x4*)(J.s[j] + idx);
  f32x4 a = ps[0], b = ps[1];
  s16x8 o;
  #pragma unroll
  for (int i=0;i<4;i++){ o[i]=(short)f2b(a[i]); o[4+i]=(short)f2b(b[i]); }
  *(s16x8*)(J.d[j] + idx) = o;
}

// W2d^T (for Wcomp gemm): out[r*128+p] = W2d[p*256+r]
__global__ __launch_bounds__(256) void tr_w2d(const u16* __restrict__ in, u16* __restrict__ out){
  int idx = blockIdx.x*256 + threadIdx.x;  // 32768
  int r = idx>>7, p = idx&127;
  out[idx] = in[p*256 + r];
}

// pb[g] = sum_p Wih_d[g, 256+p] * b2d[p]   (f32)
__global__ __launch_bounds__(256) void pb_k(const float* __restrict__ Wihd, const float* __restrict__ b2d,
                                            float* __restrict__ pb){
  int g = blockIdx.x*256 + threadIdx.x;    // 2048
  const float* row = Wihd + (size_t)g*384 + 256;
  float s = 0.f;
  for (int p=0;p<128;p++) s += row[p]*b2d[p];
  pb[g] = s;
}

// ---------------- LayerNorm stats ----------------
__global__ __launch_bounds__(256) void ln_stats(const float* __restrict__ x,
                                                float* __restrict__ mu, float* __restrict__ rstd){
  int b = blockIdx.x;
  const float* xb = x + (size_t)b*32768;
  float s1=0.f, s2=0.f;
  for (int i = threadIdx.x*4; i < 32768; i += 256*4){
    f32x4 v = *(const f32x4*)(xb+i);
    #pragma unroll
    for (int j=0;j<4;j++){ float f = v[j]; s1+=f; s2+=f*f; }
  }
  #pragma unroll
  for (int o=32;o>0;o>>=1){ s1 += __shfl_down(s1,o); s2 += __shfl_down(s2,o); }
  __shared__ float r1[4], r2[4];
  int w = threadIdx.x>>6;
  if ((threadIdx.x&63)==0){ r1[w]=s1; r2[w]=s2; }
  __syncthreads();
  if (threadIdx.x==0){
    float a=0.f,c=0.f;
    for (int i=0;i<4;i++){ a+=r1[i]; c+=r2[i]; }
    float m=a/32768.f, v=c/32768.f-m*m;
    mu[b]=m; rstd[b]=1.f/sqrtf(v+1e-5f);
  }
}

// ---------------- fused LN + encode GEMM ----------------
__global__ __launch_bounds__(256) void ln_gemm(const float* __restrict__ x,
    const float* __restrict__ mu, const float* __restrict__ rstd,
    const float* __restrict__ g, const float* __restrict__ bn,
    const u16* __restrict__ Wb, const float* __restrict__ be, u16* __restrict__ xe){
  __shared__ __align__(16) u16 As[128*32];
  __shared__ __align__(16) u16 Ws[128*32];
  int tid=threadIdx.x, lane=tid&63, wid=tid>>6;
  int wr=wid>>1, wc=wid&1;
  long m0=(long)blockIdx.y*128, n0=(long)blockIdx.x*128;
  int lr=lane&15, lk=(lane>>4)*8;
  f32x4 acc[4][4];
  #pragma unroll
  for (int i=0;i<4;i++)
    #pragma unroll
    for (int j=0;j<4;j++) acc[i][j]=(f32x4){0.f,0.f,0.f,0.f};

  for (int k0=0;k0<128;k0+=32){
    __syncthreads();
    #pragma unroll
    for (int c=tid;c<512;c+=256){
      int row=c>>2, kb=(c&3)*8;
      long R=m0+row;
      int b=(int)(R>>8), tt=(int)(R&255);
      float m=mu[b], rs=rstd[b];
      const f32x4* px=(const f32x4*)(x + R*128 + k0+kb);
      const f32x4* pg=(const f32x4*)(g + tt*128 + k0+kb);
      const f32x4* pb=(const f32x4*)(bn + tt*128 + k0+kb);
      f32x4 x0=px[0], x1=px[1], g0=pg[0], g1=pg[1], b0=pb[0], b1=pb[1];
      s16x8 o;
      #pragma unroll
      for (int j=0;j<4;j++){
        o[j]   = (short)f2b((x0[j]-m)*rs*g0[j] + b0[j]);
        o[4+j] = (short)f2b((x1[j]-m)*rs*g1[j] + b1[j]);
      }
      *(s16x8*)(As + row*32 + kb) = o;
    }
    #pragma unroll
    for (int c=tid;c<512;c+=256){
      int row=c>>2, kb=(c&3)*8;
      *(s16x8*)(Ws + row*32 + kb) = *(const s16x8*)(Wb + (n0+row)*128 + k0+kb);
    }
    __syncthreads();
    bv8 af[4], bf[4];
    #pragma unroll
    for (int i=0;i<4;i++) af[i] = ldf(As + (wr*64+i*16+lr)*32 + lk);
    #pragma unroll
    for (int j=0;j<4;j++) bf[j] = ldf(Ws + (wc*64+j*16+lr)*32 + lk);
    #pragma unroll
    for (int i=0;i<4;i++)
      #pragma unroll
      for (int j=0;j<4;j++) acc[i][j] = mfma16(af[i], bf[j], acc[i][j]);
  }
  #pragma unroll
  for (int i=0;i<4;i++)
    #pragma unroll
    for (int j=0;j<4;j++)
      #pragma unroll
      for (int r=0;r<4;r++){
        int m = wr*64+i*16+(lane>>4)*4+r;
        int n = wc*64+j*16+lr;
        float v = acc[i][j][r] + be[n0+n];
        xe[(m0+m)*256 + n0+n] = f2b(fmaxf(v,0.f));
      }
}

// ---------------- generic GEMM ----------------
template<int BM, int BN, bool RELU, bool OUTF32>
__global__ __launch_bounds__(256) void gemm_bt(const u16* __restrict__ A, int lda,
                                               const u16* __restrict__ W, int ldw,
                                               const float* __restrict__ bias1, const float* __restrict__ bias2,
                                               u16* __restrict__ Cb, float* __restrict__ Cf, int ldc, int K){
  constexpr int BK=32;
  constexpr int FM=BM/32, FN=BN/32;
  __shared__ __align__(16) u16 As[BM*BK];
  __shared__ __align__(16) u16 Ws[BN*BK];
  int tid=threadIdx.x, lane=tid&63, wid=tid>>6;
  int wr=wid>>1, wc=wid&1;
  long m0=(long)blockIdx.y*BM, n0=(long)blockIdx.x*BN;
  int lr=lane&15, lk=(lane>>4)*8;
  f32x4 acc[FM][FN];
  #pragma unroll
  for (int i=0;i<FM;i++)
    #pragma unroll
    for (int j=0;j<FN;j++) acc[i][j] = (f32x4){0.f,0.f,0.f,0.f};
  for (int k0=0;k0<K;k0+=BK){
    __syncthreads();
    #pragma unroll
    for (int c=tid;c<BM*4;c+=256){
      int row=c>>2, kb=(c&3)*8;
      *(s16x8*)(As + row*BK + kb) = *(const s16x8*)(A + (m0+row)*lda + k0+kb);
    }
    #pragma unroll
    for (int c=tid;c<BN*4;c+=256){
      int row=c>>2, kb=(c&3)*8;
      *(s16x8*)(Ws + row*BK + kb) = *(const s16x8*)(W + (n0+row)*ldw + k0+kb);
    }
    __syncthreads();
    bv8 af[FM], bf[FN];
    #pragma unroll
    for (int i=0;i<FM;i++) af[i] = ldf(As + (wr*(BM/2)+i*16+lr)*BK + lk);
    #pragma unroll
    for (int j=0;j<FN;j++) bf[j] = ldf(Ws + (wc*(BN/2)+j*16+lr)*BK + lk);
    #pragma unroll
    for (int i=0;i<FM;i++)
      #pragma unroll
      for (int j=0;j<FN;j++) acc[i][j] = mfma16(af[i], bf[j], acc[i][j]);
  }
  #pragma unroll
  for (int i=0;i<FM;i++)
    #pragma unroll
    for (int j=0;j<FN;j++)
      #pragma unroll
      for (int r=0;r<4;r++){
        int m = wr*(BM/2)+i*16+(lane>>4)*4+r;
        int n = wc*(BN/2)+j*16+lr;
        float v = acc[i][j][r];
        if (bias1) v += bias1[n0+n];
        if (bias2) v += bias2[n0+n];
        if (RELU) v = fmaxf(v,0.f);
        if (OUTF32) Cf[(m0+m)*ldc + n0+n] = v;
        else        Cb[(m0+m)*ldc + n0+n] = f2b(v);
      }
}

// ================= persistent encoder =================
// grid 256: grp = bx&7 (dir*4+bt), kc = bx>>3 (16 cells)
struct EncP {
  const u16* xe; const int* lens;
  const u16 *Wihf,*Whhf,*Wihb,*Whhb;
  const float *bif,*bhf,*bib,*bhb;
  u16 *hf0,*hf1,*hb0,*hb1,*pooled;
  unsigned* flags;
};

__global__ __launch_bounds__(256,1) void enc_persist(EncP P){
  __shared__ __align__(16) u16 Wl[64*776];
  __shared__ __align__(16) u16 As[2*128*72];
  __shared__ __align__(16) u16 Hs[128*16];
  const int tid=threadIdx.x, lane=tid&63, w=tid>>6;
  const int bx=blockIdx.x;
  const int grp=bx&7, kc=bx>>3;
  const int dir=grp>>2, bt=grp&3;
  const int lr=lane&15, lk=(lane>>4)*8;
  unsigned* flags = P.flags + grp*2048;
  const u16* Wih = dir? P.Wihb : P.Wihf;
  const u16* Whh = dir? P.Whhb : P.Whhf;
  const float* bi = dir? P.bib : P.bif;
  const float* bh = dir? P.bhb : P.bhf;
  u16* h0 = dir? P.hb0 : P.hf0;
  u16* h1 = dir? P.hb1 : P.hf1;

  for (int idx=tid; idx<64*96; idx+=256){
    int row=idx/96, col=(idx%96)*8;
    int g=row>>4, c=row&15;
    size_t grow=(size_t)(g*512 + kc*16 + c);
    const u16* src = (col<256)? (Wih + grow*256 + col) : (Whh + grow*512 + (col-256));
    *(s16x8*)(Wl + row*776 + col) = *(const s16x8*)src;
  }
  const int cg = kc*16 + lr;
  const float b_i=bi[cg]+bh[cg], b_f=bi[512+cg]+bh[512+cg];
  const float b_g=bi[1024+cg]+bh[1024+cg], b_o=bi[1536+cg]+bh[1536+cg];
  const int row_s=tid>>1, c0s=(tid&1)*32;
  const int slen = P.lens[bt*128+row_s];
  const size_t arow=(size_t)(bt*128+row_s);
  int elen[2][4]; float cs[2][4], hh[2][4], asum[2][4];
  #pragma unroll
  for (int i=0;i<2;i++)
    #pragma unroll
    for (int r=0;r<4;r++){
      int m=w*32+i*16+(lane>>4)*4+r;
      elen[i][r]=P.lens[bt*128+m];
      cs[i][r]=0.f; hh[i][r]=0.f; asum[i][r]=0.f;
    }

  auto sth2 = [&](int b, const u64* r){
    u16* dst = As + b*9216 + row_s*72 + c0s;
    #pragma unroll
    for (int j=0;j<8;j++) *(u64*)(dst + j*4) = r[j];
  };
  auto ldrow = [&](u64* r, const u16* src){
    #pragma unroll
    for (int j=0;j<8;j++) r[j] = *(const u64*)(src + j*4);
  };
  auto kit = [&](f32x4 (&acc)[2][4], int b, int wcol){
    const u16* base = As + b*9216;
    #pragma unroll
    for (int kk=0;kk<2;kk++){
      bv8 a0=ldf(base+(w*32+lr)*72+kk*32+lk);
      bv8 a1=ldf(base+(w*32+16+lr)*72+kk*32+lk);
      #pragma unroll
      for (int g=0;g<4;g++){
        bv8 bf=ldf(Wl+(g*16+lr)*776 + wcol + kk*32+lk);
        acc[0][g]=mfma16(a0,bf,acc[0][g]);
        acc[1][g]=mfma16(a1,bf,acc[1][g]);
      }
    }
  };
  auto xpart = [&](int tt, f32x4 (&xacc)[2][4]){
    u64 px[4][8];
    const u16* xr = P.xe + (arow*256 + (size_t)tt)*256 + c0s;
    #pragma unroll
    for (int k=0;k<4;k++) ldrow(px[k], xr + k*64);
    sth2(0, px[0]);
    #pragma unroll
    for (int k=0;k<4;k++){
      __syncthreads();
      if (k<3) sth2((k+1)&1, px[k+1]);
      __syncthreads();
      kit(xacc, k&1, k*64);
    }
  };

  __syncthreads();
  f32x4 xacc[2][4];
  #pragma unroll
  for (int i=0;i<2;i++)
    #pragma unroll
    for (int g=0;g<4;g++) xacc[i][g]=(f32x4){0.f,0.f,0.f,0.f};
  xpart(dir? (slen-1) : 0, xacc);

  for (int t=0;t<256;t++){
    const u16* hp = (t&1)? h1 : h0;
    u16*       hn = (t&1)? h0 : h1;
    waitflags(flags, 0, 32, (unsigned)t);
    f32x4 acc[2][4];
    #pragma unroll
    for (int i=0;i<2;i++)
      #pragma unroll
      for (int g=0;g<4;g++) acc[i][g]=xacc[i][g];
    // h-part K=512: ring-4 plain-load pipeline
    {
      u64 rg[4][8];
      const u16* hr = hp + arow*512 + c0s;
      #pragma unroll
      for (int q=0;q<4;q++) ldrow(rg[q], hr + q*64);
      #pragma unroll
      for (int k=0;k<8;k++){
        __syncthreads();
        sth2(k&1, rg[k&3]);
        if (k+4<8) ldrow(rg[k&3], hr + (k+4)*64);
        __syncthreads();
        kit(acc, k&1, 256+k*64);
      }
    }
    #pragma unroll
    for (int i=0;i<2;i++)
      #pragma unroll
      for (int r=0;r<4;r++){
        int m=w*32+i*16+(lane>>4)*4+r;
        if (t<elen[i][r]){
          float iv=sigm(acc[i][0][r]+b_i), fv=sigm(acc[i][1][r]+b_f);
          float gv=tanh_(acc[i][2][r]+b_g), ov=sigm(acc[i][3][r]+b_o);
          float c2=fv*cs[i][r]+iv*gv, h2v=ov*tanh_(c2);
          cs[i][r]=c2; hh[i][r]=h2v; asum[i][r]+=h2v;
        }
        Hs[m*16+lr]=f2b(hh[i][r]);
      }
    __syncthreads();
    #pragma unroll
    for (int q=0;q<2;q++){
      int cc=tid*2+q, sm=cc>>2, pt=cc&3;
      *(u64*)(hn + (size_t)(bt*128+sm)*512 + kc*16 + pt*4) = *(const u64*)(Hs + sm*16 + pt*4);
    }
    arrive(flags, kc, (unsigned)(t+1));
    // overlap window: x-part gates for t+1
    #pragma unroll
    for (int i=0;i<2;i++)
      #pragma unroll
      for (int g=0;g<4;g++) xacc[i][g]=(f32x4){0.f,0.f,0.f,0.f};
    if (t<255){
      int tp=t+1;
      xpart(dir? max(slen-1-tp,0) : tp, xacc);
    }
  }
  #pragma unroll
  for (int i=0;i<2;i++)
    #pragma unroll
    for (int r=0;r<4;r++){
      int m=w*32+i*16+(lane>>4)*4+r;
      P.pooled[(size_t)(bt*128+m)*1024 + (size_t)dir*512 + cg]=f2b(asum[i][r]/(float)elen[i][r]);
    }
}

// ================= persistent decoder (2 hops/step via Wcomp trick) =================
// grid 128: bt=bx&3, kc=bx>>2 (16 cells / 64 gate rows)
// step t: G: gates = gix(+pb) + gh(=Whh.h_t, precomputed) + Wcomp.r1_t -> cell -> h_{t+1}  [hop G]
//         F: gh' = Whh.h_{t+1} (all blocks); kc<16 fused: r1_{t+1}=relu(W1d.h_{t+1}+b1)    [hop F]
//         kc in [16,24): pose_t = W2d.r1_t + b2 -> outd[t-1]  (shadow, no flag)
struct DecP {
  const u16 *Whhd, *Wcmp, *W1d, *W2d;
  const float *gix, *gp0, *pb, *b1d, *b2d;
  u16 *h0,*h1,*r1a,*r1b;
  float* outd;
  unsigned* flags;   // [0..32) G-flags, [32..48) F-flags (x32 stride)
};

__global__ __launch_bounds__(256,1) void dec_persist(DecP P){
  __shared__ __align__(16) u16 Wh [64*520];
  __shared__ __align__(16) u16 WcL[64*264];
  __shared__ __align__(16) u16 F12[16*520];
  __shared__ __align__(16) u16 As[2*128*72];
  __shared__ __align__(16) u16 Hs[128*16];
  const int tid=threadIdx.x, lane=tid&63, w=tid>>6;
  const int bx=blockIdx.x, bt=bx&3, kc=bx>>2;
  const int lr=lane&15, lk=(lane>>4)*8;
  unsigned* flags = P.flags + (8+bt)*2048;

  for (int idx=tid; idx<64*64; idx+=256){
    int row=idx>>6, col=(idx&63)*8;
    int g=row>>4, c=row&15;
    size_t grow=(size_t)(g*512+kc*16+c);
    *(s16x8*)(Wh + row*520 + col) = *(const s16x8*)(P.Whhd + grow*512 + col);
  }
  for (int idx=tid; idx<64*32; idx+=256){
    int row=idx>>5, col=(idx&31)*8;
    int g=row>>4, c=row&15;
    size_t grow=(size_t)(g*512+kc*16+c);
    *(s16x8*)(WcL + row*264 + col) = *(const s16x8*)(P.Wcmp + grow*256 + col);
  }
  if (kc<16){
    for (int idx=tid; idx<16*64; idx+=256){
      int rr=idx>>6, col=(idx&63)*8;
      *(s16x8*)(F12 + rr*520 + col) = *(const s16x8*)(P.W1d + (size_t)(kc*16+rr)*512 + col);
    }
  } else if (kc<24){
    for (int idx=tid; idx<16*32; idx+=256){
      int rr=idx>>5, col=(idx&31)*8;
      *(s16x8*)(F12 + rr*264 + col) = *(const s16x8*)(P.W2d + (size_t)((kc-16)*16+rr)*256 + col);
    }
  }
  float gx[2][4][4]; float pbr[4];
  #pragma unroll
  for (int i=0;i<2;i++)
    #pragma unroll
    for (int g=0;g<4;g++)
      #pragma unroll
      for (int r=0;r<4;r++){
        int m=w*32+i*16+(lane>>4)*4+r;
        gx[i][g][r]=P.gix[(size_t)(bt*128+m)*2048 + (size_t)g*512 + kc*16 + lr];
      }
  #pragma unroll
  for (int g=0;g<4;g++) pbr[g] = P.pb[(size_t)g*512 + kc*16 + lr];
  const float b1=(kc<16)? P.b1d[kc*16+lr] : 0.f;
  const float b2=(kc>=16&&kc<24)? P.b2d[(kc-16)*16+lr] : 0.f;
  const int row_s=tid>>1, c0s=(tid&1)*32;
  const size_t arow=(size_t)(bt*128+row_s);
  float cs[2][4];
  f32x4 gh[2][4];
  #pragma unroll
  for (int i=0;i<2;i++){
    #pragma unroll
    for (int r=0;r<4;r++) cs[i][r]=0.f;
    #pragma unroll
    for (int g=0;g<4;g++) gh[i][g]=(f32x4){0.f,0.f,0.f,0.f};
  }

  auto sth2=[&](int b, const u64* r){
    u16* dst = As + b*9216 + row_s*72 + c0s;
    #pragma unroll
    for (int j=0;j<8;j++) *(u64*)(dst + j*4) = r[j];
  };
  auto ldrow=[&](u64* r, const u16* src){
    #pragma unroll
    for (int j=0;j<8;j++) r[j] = *(const u64*)(src + j*4);
  };
  auto lda2=[&](bv8& a0, bv8& a1, int b, int kk){
    const u16* base = As + b*9216;
    a0=ldf(base+(w*32+lr)*72+kk*32+lk);
    a1=ldf(base+(w*32+16+lr)*72+kk*32+lk);
  };
  auto kitWh=[&](f32x4 (&acc)[2][4], int b, int wcol){
    #pragma unroll
    for (int kk=0;kk<2;kk++){
      bv8 a0,a1; lda2(a0,a1,b,kk);
      #pragma unroll
      for (int g=0;g<4;g++){
        bv8 bf=ldf(Wh+(g*16+lr)*520 + wcol + kk*32+lk);
        acc[0][g]=mfma16(a0,bf,acc[0][g]);
        acc[1][g]=mfma16(a1,bf,acc[1][g]);
      }
    }
  };
  auto kitWc=[&](f32x4 (&acc)[2][4], int b, int wcol){
    #pragma unroll
    for (int kk=0;kk<2;kk++){
      bv8 a0,a1; lda2(a0,a1,b,kk);
      #pragma unroll
      for (int g=0;g<4;g++){
        bv8 bf=ldf(WcL+(g*16+lr)*264 + wcol + kk*32+lk);
        acc[0][g]=mfma16(a0,bf,acc[0][g]);
        acc[1][g]=mfma16(a1,bf,acc[1][g]);
      }
    }
  };
  auto kitf1=[&](f32x4 (&fa)[2], int b, int fcol){
    #pragma unroll
    for (int kk=0;kk<2;kk++){
      bv8 a0,a1; lda2(a0,a1,b,kk);
      bv8 bf=ldf(F12 + lr*520 + fcol + kk*32+lk);
      fa[0]=mfma16(a0,bf,fa[0]); fa[1]=mfma16(a1,bf,fa[1]);
    }
  };
  auto kitf2=[&](f32x4 (&fa)[2], int b, int fcol){
    #pragma unroll
    for (int kk=0;kk<2;kk++){
      bv8 a0,a1; lda2(a0,a1,b,kk);
      bv8 bf=ldf(F12 + lr*264 + fcol + kk*32+lk);
      fa[0]=mfma16(a0,bf,fa[0]); fa[1]=mfma16(a1,bf,fa[1]);
    }
  };

  __syncthreads();   // weights staged
  for (int t=0;t<256;t++){
    const u16* r1rd = (t&1)? P.r1b : P.r1a;
    u16* hn = (t&1)? P.h0 : P.h1;
    f32x4 acc[2][4];
    if (t==0){
      #pragma unroll
      for (int i=0;i<2;i++)
        #pragma unroll
        for (int g=0;g<4;g++)
          #pragma unroll
          for (int r=0;r<4;r++){
            int m=w*32+i*16+(lane>>4)*4+r;
            acc[i][g][r] = gx[i][g][r] + P.gp0[(size_t)(bt*128+m)*2048 + (size_t)g*512 + kc*16 + lr];
          }
    } else {
      waitflags(flags, 32, 16, (unsigned)t);   // r1_t ready
      #pragma unroll
      for (int i=0;i<2;i++)
        #pragma unroll
        for (int g=0;g<4;g++){
          f32x4 gv = (f32x4){gx[i][g][0]+pbr[g], gx[i][g][1]+pbr[g], gx[i][g][2]+pbr[g], gx[i][g][3]+pbr[g]};
          acc[i][g] = gh[i][g] + gv;
        }
      // Wcomp . r1_t  (K=256)
      u64 rr4[4][8];
      const u16* rb = r1rd + arow*256 + c0s;
      #pragma unroll
      for (int q=0;q<4;q++) ldrow(rr4[q], rb + q*64);
      sth2(0, rr4[0]);
      #pragma unroll
      for (int k=0;k<4;k++){
        __syncthreads();
        if (k<3) sth2((k+1)&1, rr4[k+1]);
        __syncthreads();
        kitWc(acc, k&1, k*64);
      }
    }
    // cell
    #pragma unroll
    for (int i=0;i<2;i++)
      #pragma unroll
      for (int r=0;r<4;r++){
        float iv=sigm(acc[i][0][r]), fv=sigm(acc[i][1][r]);
        float gv=tanh_(acc[i][2][r]), ov=sigm(acc[i][3][r]);
        float c2=fv*cs[i][r]+iv*gv, h2v=ov*tanh_(c2);
        cs[i][r]=c2;
        int m=w*32+i*16+(lane>>4)*4+r;
        Hs[m*16+lr]=f2b(h2v);
      }
    __syncthreads();
    #pragma unroll
    for (int q=0;q<2;q++){
      int cc=tid*2+q, sm=cc>>2, pt=cc&3;
      *(u64*)(hn + (size_t)(bt*128+sm)*512 + kc*16 + pt*4) = *(const u64*)(Hs + sm*16 + pt*4);
    }
    arrive(flags, kc, (unsigned)(t+1));          // G flag
    // pose_t -> outd[t-1] (blocks 16..23, shadow work, r1_t already acquired)
    if (kc>=16 && kc<24 && t>0){
      f32x4 fa2[2]; fa2[0]=(f32x4){0.f,0.f,0.f,0.f}; fa2[1]=fa2[0];
      u64 rp[4][8];
      const u16* rb = r1rd + arow*256 + c0s;
      #pragma unroll
      for (int q=0;q<4;q++) ldrow(rp[q], rb + q*64);
      sth2(0, rp[0]);
      #pragma unroll
      for (int k=0;k<4;k++){
        __syncthreads();
        if (k<3) sth2((k+1)&1, rp[k+1]);
        __syncthreads();
        kitf2(fa2, k&1, k*64);
      }
      int pc=(kc-16)*16+lr;
      #pragma unroll
      for (int i=0;i<2;i++)
        #pragma unroll
        for (int r=0;r<4;r++){
          int m=w*32+i*16+(lane>>4)*4+r;
          __builtin_nontemporal_store(fa2[i][r]+b2, P.outd + (size_t)(bt*128+m)*32768 + (size_t)(t-1)*128 + pc);
        }
    }
    waitflags(flags, 0, 32, (unsigned)(t+1));    // h_{t+1} ready
    // F window: gh' = Whh.h_{t+1}; kc<16 fused r1_{t+1}
    f32x4 gn[2][4]; f32x4 fa[2];
    #pragma unroll
    for (int i=0;i<2;i++)
      #pragma unroll
      for (int g=0;g<4;g++) gn[i][g]=(f32x4){0.f,0.f,0.f,0.f};
    fa[0]=(f32x4){0.f,0.f,0.f,0.f}; fa[1]=fa[0];
    {
      u64 rg[4][8];
      const u16* hb = hn + arow*512 + c0s;
      #pragma unroll
      for (int q=0;q<4;q++) ldrow(rg[q], hb + q*64);
      #pragma unroll
      for (int k=0;k<8;k++){
        __syncthreads();
        sth2(k&1, rg[k&3]);
        if (k+4<8) ldrow(rg[k&3], hb + (k+4)*64);
        __syncthreads();
        kitWh(gn, k&1, k*64);
        if (kc<16) kitf1(fa, k&1, k*64);
      }
    }
    #pragma unroll
    for (int i=0;i<2;i++)
      #pragma unroll
      for (int g=0;g<4;g++) gh[i][g]=gn[i][g];
    if (kc<16){
      u16* r1w = (t&1)? P.r1a : P.r1b;           // parity (t+1)&1
      #pragma unroll
      for (int i=0;i<2;i++)
        #pragma unroll
        for (int r=0;r<4;r++){
          int m=w*32+i*16+(lane>>4)*4+r;
          Hs[m*16+lr]=f2b(fmaxf(fa[i][r]+b1,0.f));
        }
      __syncthreads();
      #pragma unroll
      for (int q=0;q<2;q++){
        int cc=tid*2+q, sm=cc>>2, pt=cc&3;
        *(u64*)(r1w + (size_t)(bt*128+sm)*256 + kc*16 + pt*4) = *(const u64*)(Hs + sm*16 + pt*4);
      }
      arrive(flags, 32+kc, (unsigned)(t+1));     // F flag
    }
  }
  // epilogue: pose_256 -> outd[255]
  if (kc>=16 && kc<24){
    waitflags(flags, 32, 16, 256u);
    const u16* r1rd = P.r1a;                      // parity (256)&1 = 0
    f32x4 fa2[2]; fa2[0]=(f32x4){0.f,0.f,0.f,0.f}; fa2[1]=fa2[0];
    u64 rp[4][8];
    const u16* rb = r1rd + arow*256 + c0s;
    #pragma unroll
    for (int q=0;q<4;q++) ldrow(rp[q], rb + q*64);
    sth2(0, rp[0]);
    #pragma unroll
    for (int k=0;k<4;k++){
      __syncthreads();
      if (k<3) sth2((k+1)&1, rp[k+1]);
      __syncthreads();
      kitf2(fa2, k&1, k*64);
    }
    int pc=(kc-16)*16+lr;
    #pragma unroll
    for (int i=0;i<2;i++)
      #pragma unroll
      for (int r=0;r<4;r++){
        int m=w*32+i*16+(lane>>4)*4+r;
        __builtin_nontemporal_store(fa2[i][r]+b2, P.outd + (size_t)(bt*128+m)*32768 + (size_t)255*128 + pc);
      }
  }
}

__global__ __launch_bounds__(512) void len_cast(const int* __restrict__ lens, float* __restrict__ out){
  int i = threadIdx.x;
  if (i < 512) out[i] = (float)lens[i];
}

// ============================== host ==============================
extern "C" void kernel_launch(void* const* d_in, const int* in_sizes, int n_in,
                              void* d_out, int out_size, void* d_ws, size_t ws_size,
                              hipStream_t stream){
  (void)in_sizes; (void)n_in; (void)out_size; (void)ws_size;
  const float* x      = (const float*)d_in[0];
  const int*   lens   = (const int*)d_in[1];
  const float* ng     = (const float*)d_in[2];
  const float* nb     = (const float*)d_in[3];
  const float* We     = (const float*)d_in[4];
  const float* be     = (const float*)d_in[5];
  const float* Wih_f  = (const float*)d_in[6];
  const float* Whh_f  = (const float*)d_in[7];
  const float* bih_f  = (const float*)d_in[8];
  const float* bhh_f  = (const float*)d_in[9];
  const float* Wih_b  = (const float*)d_in[10];
  const float* Whh_b  = (const float*)d_in[11];
  const float* bih_b  = (const float*)d_in[12];
  const float* bhh_b  = (const float*)d_in[13];
  const float* W1e    = (const float*)d_in[14];
  const float* b1e    = (const float*)d_in[15];
  const float* W2e    = (const float*)d_in[16];
  const float* b2e    = (const float*)d_in[17];
  const float* Wd     = (const float*)d_in[18];
  const float* bd     = (const float*)d_in[19];
  const float* Wp1    = (const float*)d_in[20];
  const float* bp1    = (const float*)d_in[21];
  const float* Wp2    = (const float*)d_in[22];
  const float* bp2    = (const float*)d_in[23];
  const float* Wih_d  = (const float*)d_in[24];
  const float* Whh_d  = (const float*)d_in[25];
  const float* bih_d  = (const float*)d_in[26];
  const float* bhh_d  = (const float*)d_in[27];
  const float* W1d    = (const float*)d_in[28];
  const float* b1d    = (const float*)d_in[29];
  const float* W2d    = (const float*)d_in[30];
  const float* b2d    = (const float*)d_in[31];

  char* p = (char*)d_ws;
  auto carve = [&](size_t bytes)->void*{ void* r=(void*)p; p += (bytes+255)&~(size_t)255; return r; };
  float* mu   = (float*)carve(512*4);
  float* rstd = (float*)carve(512*4);
  u16* xe     = (u16*)carve((size_t)33554432*2);
  u16* wWe  = (u16*)carve(32768*2);
  u16* wIhf = (u16*)carve(524288*2);
  u16* wHhf = (u16*)carve(1048576*2);
  u16* wIhb = (u16*)carve(524288*2);
  u16* wHhb = (u16*)carve(1048576*2);
  u16* wW1e = (u16*)carve(524288*2);
  u16* wW2e = (u16*)carve(131072*2);
  u16* wWd  = (u16*)carve(65536*2);
  u16* wWp1 = (u16*)carve(65536*2);
  u16* wWp2 = (u16*)carve(32768*2);
  u16* wIhd = (u16*)carve(786432*2);
  u16* wHhd = (u16*)carve(1048576*2);
  u16* wW1d = (u16*)carve(131072*2);
  u16* wW2d = (u16*)carve(32768*2);
  u16* wW2dT  = (u16*)carve(32768*2);
  u16* wWcomp = (u16*)carve(524288*2);
  float* pbv  = (float*)carve(2048*4);
  float* gp0f = (float*)carve((size_t)1048576*4);
  u16* hf0  = (u16*)carve(524288);
  u16* hf1  = (u16*)carve(524288);
  u16* hb0  = (u16*)carve(524288);
  u16* hb1  = (u16*)carve(524288);
  u16* hd0  = (u16*)carve(524288);
  u16* hd1  = (u16*)carve(524288);
  u16* r1a  = (u16*)carve(262144);
  u16* r1b  = (u16*)carve(262144);
  u16* pooled = (u16*)carve(1048576);
  u16* out1   = (u16*)carve(524288);
  u16* zlat   = (u16*)carve(262144);
  u16* x0     = (u16*)carve(262144);
  u16* t0     = (u16*)carve(262144);
  float* gix  = (float*)carve(4194304);
  u16* pose   = (u16*)carve(131072);
  unsigned* barflags = (unsigned*)carve(12*2048*4);

  float* out_x   = (float*)d_out;
  float* out_dec = out_x + 16777216;
  float* out_len = out_x + 33554432;

  hipMemcpyAsync(out_x, x, (size_t)16777216*4, hipMemcpyDeviceToDevice, stream);
  hipMemsetAsync(hf0,0,524288,stream);
  hipMemsetAsync(hb0,0,524288,stream);
  hipMemsetAsync(barflags,0,12*2048*4,stream);

  CvtJobs J;
  const float* srcs[14] = {We,Wih_f,Whh_f,Wih_b,Whh_b,W1e,W2e,Wd,Wp1,Wp2,Wih_d,Whh_d,W1d,W2d};
  u16* dsts[14] = {wWe,wIhf,wHhf,wIhb,wHhb,wW1e,wW2e,wWd,wWp1,wWp2,wIhd,wHhd,wW1d,wW2d};
  int ns[14] = {32768,524288,1048576,524288,1048576,524288,131072,65536,65536,32768,786432,1048576,131072,32768};
  int blk=0;
  for (int i=0;i<14;i++){ J.s[i]=srcs[i]; J.d[i]=dsts[i]; J.start[i]=blk; blk += ns[i]/2048; }
  cvt_w<<<blk,256,0,stream>>>(J);

  // decoder precompute: W2d^T, pb, Wcomp = Wih_p @ W2d
  tr_w2d<<<128,256,0,stream>>>(wW2d, wW2dT);
  pb_k<<<8,256,0,stream>>>(Wih_d, b2d, pbv);
  gemm_bt<64,64,false,false><<<dim3(4,32),256,0,stream>>>(wIhd+256,384, wW2dT,128, nullptr,nullptr, wWcomp,nullptr,256,128);

  ln_stats<<<512,256,0,stream>>>(x,mu,rstd);
  ln_gemm<<<dim3(2,1024),256,0,stream>>>(x,mu,rstd,ng,nb,wWe,be,xe);

  EncP EP = {xe,lens,wIhf,wHhf,wIhb,wHhb,bih_f,bhh_f,bih_b,bhh_b,hf0,hf1,hb0,hb1,pooled,barflags};
  {
    void* ea[] = {&EP};
    if (hipLaunchCooperativeKernel((void*)enc_persist, dim3(256), dim3(256), ea, 0, stream) != hipSuccess)
      enc_persist<<<256,256,0,stream>>>(EP);
  }

  gemm_bt<64,64,true ,false><<<dim3(8,8),256,0,stream>>>(pooled,1024,wW1e,1024,b1e,nullptr,out1,nullptr,512,1024);
  gemm_bt<64,64,false,false><<<dim3(4,8),256,0,stream>>>(out1,512,wW2e,512,b2e,nullptr,zlat,nullptr,256,512);
  gemm_bt<64,64,true ,false><<<dim3(4,8),256,0,stream>>>(zlat,256,wWd,256,bd,nullptr,x0,nullptr,256,256);
  gemm_bt<64,64,true ,false><<<dim3(4,8),256,0,stream>>>(x0,256,wWp1,256,bp1,nullptr,t0,nullptr,256,256);
  gemm_bt<64,64,false,false><<<dim3(2,8),256,0,stream>>>(t0,256,wWp2,256,bp2,nullptr,pose,nullptr,128,256);
  // gix = x0 @ Wih_x^T + bih + bhh  (f32)
  gemm_bt<64,128,false,true><<<dim3(16,8),256,0,stream>>>(x0,256,wIhd,384,bih_d,bhh_d,nullptr,gix,2048,256);
  // gp0 = pose0 @ Wih_p^T (f32)
  gemm_bt<64,128,false,true><<<dim3(16,8),256,0,stream>>>(pose,128,wIhd+256,384,nullptr,nullptr,nullptr,gp0f,2048,128);

  DecP DP = {wHhd,wWcomp,wW1d,wW2d, gix,gp0f,pbv,b1d,b2d, hd0,hd1,r1a,r1b, out_dec, barflags};
  {
    void* da[] = {&DP};
    if (hipLaunchCooperativeKernel((void*)dec_persist, dim3(128), dim3(256), da, 0, stream) != hipSuccess)
      dec_persist<<<128,256,0,stream>>>(DP);
  }

  len_cast<<<1,512,0,stream>>>(lens,out_len);
}

// Round 8
// 8798.103 us; speedup vs baseline: 3.0791x; 1.0049x over previous
//
#include <hip/hip_runtime.h>
#include <stdint.h>
#include <math.h>

typedef unsigned short u16;
typedef unsigned long long u64;
typedef short s16x8 __attribute__((ext_vector_type(8)));
typedef __bf16 bv8 __attribute__((ext_vector_type(8)));
typedef float f32x4 __attribute__((ext_vector_type(4)));

#define DEV static __device__ __forceinline__

DEV float b2f(u16 x){ union{unsigned u; float f;} v; v.u=((unsigned)x)<<16; return v.f; }
DEV u16 f2b(float f){ union{float f; unsigned u;} v; v.f=f; unsigned u=v.u; u += 0x7fff + ((u>>16)&1u); return (u16)(u>>16); }
DEV float sigm(float x){ return 1.f/(1.f+__expf(-x)); }
DEV float tanh_(float x){ float cx=fminf(fmaxf(x,-20.f),20.f); float e=__expf(2.f*cx); return (e-1.f)/(e+1.f); }
DEV f32x4 mfma16(bv8 a, bv8 b, f32x4 c){ return __builtin_amdgcn_mfma_f32_16x16x32_bf16(a,b,c,0,0,0); }
DEV bv8 ldf(const u16* p){ return __builtin_bit_cast(bv8, *(const s16x8*)p); }

DEV unsigned ald4(const unsigned* p){ return __hip_atomic_load(p, __ATOMIC_RELAXED, __HIP_MEMORY_SCOPE_AGENT); }

// fence-once protocol (proven r6): plain cached state traffic; one wb on arrive, one inv on wait.
DEV void arrive(unsigned* flags, int my, unsigned e){
  __syncthreads();
  if (threadIdx.x < 64){
    __builtin_amdgcn_fence(__ATOMIC_RELEASE, "agent");
    if (threadIdx.x == 0)
      __hip_atomic_store(&flags[my*32], e, __ATOMIC_RELAXED, __HIP_MEMORY_SCOPE_AGENT);
  }
}
DEV void waitflags(unsigned* flags, int lo, int n, unsigned e){
  int t = (int)threadIdx.x;
  if (t>=lo && t<lo+n){
    while (ald4(&flags[t*32]) < e) __builtin_amdgcn_s_sleep(1);
  }
  if (t < 64) __builtin_amdgcn_fence(__ATOMIC_ACQUIRE, "agent");
  __syncthreads();
}

// ---------------- weight f32 -> bf16 conversion ----------------
struct CvtJobs { const float* s[14]; u16* d[14]; int start[14]; };

__global__ __launch_bounds__(256) void cvt_w(CvtJobs J){
  int blk = blockIdx.x, tid = threadIdx.x;
  int j = 0;
  #pragma unroll
  for (int k=1;k<14;k++) if (blk >= J.start[k]) j = k;
  size_t idx = (size_t)(blk - J.start[j])*2048 + (size_t)tid*8;
  const f32x4* ps = (const f32x4*)(J.s[j] + idx);
  f32x4 a = ps[0], b = ps[1];
  s16x8 o;
  #pragma unroll
  for (int i=0;i<4;i++){ o[i]=(short)f2b(a[i]); o[4+i]=(short)f2b(b[i]); }
  *(s16x8*)(J.d[j] + idx) = o;
}

__global__ __launch_bounds__(256) void tr_w2d(const u16* __restrict__ in, u16* __restrict__ out){
  int idx = blockIdx.x*256 + threadIdx.x;  // 32768
  int r = idx>>7, p = idx&127;
  out[idx] = in[p*256 + r];
}

__global__ __launch_bounds__(256) void pb_k(const float* __restrict__ Wihd, const float* __restrict__ b2d,
                                            float* __restrict__ pb){
  int g = blockIdx.x*256 + threadIdx.x;    // 2048
  const float* row = Wihd + (size_t)g*384 + 256;
  float s = 0.f;
  for (int p=0;p<128;p++) s += row[p]*b2d[p];
  pb[g] = s;
}

// ---------------- LayerNorm stats ----------------
__global__ __launch_bounds__(256) void ln_stats(const float* __restrict__ x,
                                                float* __restrict__ mu, float* __restrict__ rstd){
  int b = blockIdx.x;
  const float* xb = x + (size_t)b*32768;
  float s1=0.f, s2=0.f;
  for (int i = threadIdx.x*4; i < 32768; i += 256*4){
    f32x4 v = *(const f32x4*)(xb+i);
    #pragma unroll
    for (int j=0;j<4;j++){ float f = v[j]; s1+=f; s2+=f*f; }
  }
  #pragma unroll
  for (int o=32;o>0;o>>=1){ s1 += __shfl_down(s1,o); s2 += __shfl_down(s2,o); }
  __shared__ float r1[4], r2[4];
  int w = threadIdx.x>>6;
  if ((threadIdx.x&63)==0){ r1[w]=s1; r2[w]=s2; }
  __syncthreads();
  if (threadIdx.x==0){
    float a=0.f,c=0.f;
    for (int i=0;i<4;i++){ a+=r1[i]; c+=r2[i]; }
    float m=a/32768.f, v=c/32768.f-m*m;
    mu[b]=m; rstd[b]=1.f/sqrtf(v+1e-5f);
  }
}

// ---------------- fused LN + encode GEMM ----------------
__global__ __launch_bounds__(256) void ln_gemm(const float* __restrict__ x,
    const float* __restrict__ mu, const float* __restrict__ rstd,
    const float* __restrict__ g, const float* __restrict__ bn,
    const u16* __restrict__ Wb, const float* __restrict__ be, u16* __restrict__ xe){
  __shared__ __align__(16) u16 As[128*32];
  __shared__ __align__(16) u16 Ws[128*32];
  int tid=threadIdx.x, lane=tid&63, wid=tid>>6;
  int wr=wid>>1, wc=wid&1;
  long m0=(long)blockIdx.y*128, n0=(long)blockIdx.x*128;
  int lr=lane&15, lk=(lane>>4)*8;
  f32x4 acc[4][4];
  #pragma unroll
  for (int i=0;i<4;i++)
    #pragma unroll
    for (int j=0;j<4;j++) acc[i][j]=(f32x4){0.f,0.f,0.f,0.f};

  for (int k0=0;k0<128;k0+=32){
    __syncthreads();
    #pragma unroll
    for (int c=tid;c<512;c+=256){
      int row=c>>2, kb=(c&3)*8;
      long R=m0+row;
      int b=(int)(R>>8), tt=(int)(R&255);
      float m=mu[b], rs=rstd[b];
      const f32x4* px=(const f32x4*)(x + R*128 + k0+kb);
      const f32x4* pg=(const f32x4*)(g + tt*128 + k0+kb);
      const f32x4* pb=(const f32x4*)(bn + tt*128 + k0+kb);
      f32x4 x0=px[0], x1=px[1], g0=pg[0], g1=pg[1], b0=pb[0], b1=pb[1];
      s16x8 o;
      #pragma unroll
      for (int j=0;j<4;j++){
        o[j]   = (short)f2b((x0[j]-m)*rs*g0[j] + b0[j]);
        o[4+j] = (short)f2b((x1[j]-m)*rs*g1[j] + b1[j]);
      }
      *(s16x8*)(As + row*32 + kb) = o;
    }
    #pragma unroll
    for (int c=tid;c<512;c+=256){
      int row=c>>2, kb=(c&3)*8;
      *(s16x8*)(Ws + row*32 + kb) = *(const s16x8*)(Wb + (n0+row)*128 + k0+kb);
    }
    __syncthreads();
    bv8 af[4], bf[4];
    #pragma unroll
    for (int i=0;i<4;i++) af[i] = ldf(As + (wr*64+i*16+lr)*32 + lk);
    #pragma unroll
    for (int j=0;j<4;j++) bf[j] = ldf(Ws + (wc*64+j*16+lr)*32 + lk);
    #pragma unroll
    for (int i=0;i<4;i++)
      #pragma unroll
      for (int j=0;j<4;j++) acc[i][j] = mfma16(af[i], bf[j], acc[i][j]);
  }
  #pragma unroll
  for (int i=0;i<4;i++)
    #pragma unroll
    for (int j=0;j<4;j++)
      #pragma unroll
      for (int r=0;r<4;r++){
        int m = wr*64+i*16+(lane>>4)*4+r;
        int n = wc*64+j*16+lr;
        float v = acc[i][j][r] + be[n0+n];
        xe[(m0+m)*256 + n0+n] = f2b(fmaxf(v,0.f));
      }
}

// ---------------- generic GEMM ----------------
template<int BM, int BN, bool RELU, bool OUTF32>
__global__ __launch_bounds__(256) void gemm_bt(const u16* __restrict__ A, int lda,
                                               const u16* __restrict__ W, int ldw,
                                               const float* __restrict__ bias1, const float* __restrict__ bias2,
                                               u16* __restrict__ Cb, float* __restrict__ Cf, int ldc, int K){
  constexpr int BK=32;
  constexpr int FM=BM/32, FN=BN/32;
  __shared__ __align__(16) u16 As[BM*BK];
  __shared__ __align__(16) u16 Ws[BN*BK];
  int tid=threadIdx.x, lane=tid&63, wid=tid>>6;
  int wr=wid>>1, wc=wid&1;
  long m0=(long)blockIdx.y*BM, n0=(long)blockIdx.x*BN;
  int lr=lane&15, lk=(lane>>4)*8;
  f32x4 acc[FM][FN];
  #pragma unroll
  for (int i=0;i<FM;i++)
    #pragma unroll
    for (int j=0;j<FN;j++) acc[i][j] = (f32x4){0.f,0.f,0.f,0.f};
  for (int k0=0;k0<K;k0+=BK){
    __syncthreads();
    #pragma unroll
    for (int c=tid;c<BM*4;c+=256){
      int row=c>>2, kb=(c&3)*8;
      *(s16x8*)(As + row*BK + kb) = *(const s16x8*)(A + (m0+row)*lda + k0+kb);
    }
    #pragma unroll
    for (int c=tid;c<BN*4;c+=256){
      int row=c>>2, kb=(c&3)*8;
      *(s16x8*)(Ws + row*BK + kb) = *(const s16x8*)(W + (n0+row)*ldw + k0+kb);
    }
    __syncthreads();
    bv8 af[FM], bf[FN];
    #pragma unroll
    for (int i=0;i<FM;i++) af[i] = ldf(As + (wr*(BM/2)+i*16+lr)*BK + lk);
    #pragma unroll
    for (int j=0;j<FN;j++) bf[j] = ldf(Ws + (wc*(BN/2)+j*16+lr)*BK + lk);
    #pragma unroll
    for (int i=0;i<FM;i++)
      #pragma unroll
      for (int j=0;j<FN;j++) acc[i][j] = mfma16(af[i], bf[j], acc[i][j]);
  }
  #pragma unroll
  for (int i=0;i<FM;i++)
    #pragma unroll
    for (int j=0;j<FN;j++)
      #pragma unroll
      for (int r=0;r<4;r++){
        int m = wr*(BM/2)+i*16+(lane>>4)*4+r;
        int n = wc*(BN/2)+j*16+lr;
        float v = acc[i][j][r];
        if (bias1) v += bias1[n0+n];
        if (bias2) v += bias2[n0+n];
        if (RELU) v = fmaxf(v,0.f);
        if (OUTF32) Cf[(m0+m)*ldc + n0+n] = v;
        else        Cb[(m0+m)*ldc + n0+n] = f2b(v);
      }
}

// ================= persistent encoder =================
// grid 256: grp = bx&7 (dir*4+bt), kc = bx>>3 (16 cells). Direct per-lane A loads, no K-loop barriers.
struct EncP {
  const u16* xe; const int* lens;
  const u16 *Wihf,*Whhf,*Wihb,*Whhb;
  const float *bif,*bhf,*bib,*bhb;
  u16 *hf0,*hf1,*hb0,*hb1,*pooled;
  unsigned* flags;
};

__global__ __launch_bounds__(256,1) void enc_persist(EncP P){
  __shared__ __align__(16) u16 Wl[64*776];
  __shared__ __align__(16) u16 Hs[128*16];
  const int tid=threadIdx.x, lane=tid&63, w=tid>>6;
  const int bx=blockIdx.x;
  const int grp=bx&7, kc=bx>>3;
  const int dir=grp>>2, bt=grp&3;
  const int lr=lane&15, lk=(lane>>4)*8;
  unsigned* flags = P.flags + grp*2048;
  const u16* Wih = dir? P.Wihb : P.Wihf;
  const u16* Whh = dir? P.Whhb : P.Whhf;
  const float* bi = dir? P.bib : P.bif;
  const float* bh = dir? P.bhb : P.bhf;
  u16* h0 = dir? P.hb0 : P.hf0;
  u16* h1 = dir? P.hb1 : P.hf1;

  for (int idx=tid; idx<64*96; idx+=256){
    int row=idx/96, col=(idx%96)*8;
    int g=row>>4, c=row&15;
    size_t grow=(size_t)(g*512 + kc*16 + c);
    const u16* src = (col<256)? (Wih + grow*256 + col) : (Whh + grow*512 + (col-256));
    *(s16x8*)(Wl + row*776 + col) = *(const s16x8*)src;
  }
  const int cg = kc*16 + lr;
  const float b_i=bi[cg]+bh[cg], b_f=bi[512+cg]+bh[512+cg];
  const float b_g=bi[1024+cg]+bh[1024+cg], b_o=bi[1536+cg]+bh[1536+cg];
  // each wave owns 32 sample-rows as two 16-row fragments
  const int r0 = w*32 + lr, r1i = r0 + 16;
  const int slen0 = P.lens[bt*128+r0], slen1 = P.lens[bt*128+r1i];
  const u16* xb0 = P.xe + (size_t)(bt*128+r0)*65536;
  const u16* xb1 = P.xe + (size_t)(bt*128+r1i)*65536;
  int elen[2][4]; float cs[2][4], hh[2][4], asum[2][4];
  #pragma unroll
  for (int i=0;i<2;i++)
    #pragma unroll
    for (int r=0;r<4;r++){
      int m=w*32+i*16+(lane>>4)*4+r;
      elen[i][r]=P.lens[bt*128+m];
      cs[i][r]=0.f; hh[i][r]=0.f; asum[i][r]=0.f;
    }
  __syncthreads();   // weights staged

  auto xpart=[&](int t_, f32x4 (&xacc)[2][4]){
    int tt0 = dir? max(slen0-1-t_,0) : t_;
    int tt1 = dir? max(slen1-1-t_,0) : t_;
    const u16* xr0 = xb0 + (size_t)tt0*256;
    const u16* xr1 = xb1 + (size_t)tt1*256;
    #pragma unroll
    for (int k=0;k<4;k++)
      #pragma unroll
      for (int kk=0;kk<2;kk++){
        bv8 a0 = ldf(xr0 + k*64 + kk*32 + lk);
        bv8 a1 = ldf(xr1 + k*64 + kk*32 + lk);
        #pragma unroll
        for (int g=0;g<4;g++){
          bv8 bf = ldf(Wl + (g*16+lr)*776 + k*64 + kk*32 + lk);
          xacc[0][g]=mfma16(a0,bf,xacc[0][g]);
          xacc[1][g]=mfma16(a1,bf,xacc[1][g]);
        }
      }
  };

  f32x4 xacc[2][4];
  #pragma unroll
  for (int i=0;i<2;i++)
    #pragma unroll
    for (int g=0;g<4;g++) xacc[i][g]=(f32x4){0.f,0.f,0.f,0.f};
  xpart(0, xacc);

  for (int t=0;t<256;t++){
    const u16* hp = (t&1)? h1 : h0;
    u16*       hn = (t&1)? h0 : h1;
    waitflags(flags, 0, 32, (unsigned)t);
    f32x4 acc[2][4];
    #pragma unroll
    for (int i=0;i<2;i++)
      #pragma unroll
      for (int g=0;g<4;g++) acc[i][g]=xacc[i][g];
    // h-part K=512: direct per-lane plain loads (valid post-acquire), no barriers
    {
      const u16* hr0 = hp + (size_t)(bt*128+r0)*512;
      const u16* hr1 = hp + (size_t)(bt*128+r1i)*512;
      #pragma unroll
      for (int k=0;k<8;k++)
        #pragma unroll
        for (int kk=0;kk<2;kk++){
          bv8 a0 = ldf(hr0 + k*64 + kk*32 + lk);
          bv8 a1 = ldf(hr1 + k*64 + kk*32 + lk);
          #pragma unroll
          for (int g=0;g<4;g++){
            bv8 bf = ldf(Wl + (g*16+lr)*776 + 256 + k*64 + kk*32 + lk);
            acc[0][g]=mfma16(a0,bf,acc[0][g]);
            acc[1][g]=mfma16(a1,bf,acc[1][g]);
          }
        }
    }
    #pragma unroll
    for (int i=0;i<2;i++)
      #pragma unroll
      for (int r=0;r<4;r++){
        int m=w*32+i*16+(lane>>4)*4+r;
        if (t<elen[i][r]){
          float iv=sigm(acc[i][0][r]+b_i), fv=sigm(acc[i][1][r]+b_f);
          float gv=tanh_(acc[i][2][r]+b_g), ov=sigm(acc[i][3][r]+b_o);
          float c2=fv*cs[i][r]+iv*gv, h2v=ov*tanh_(c2);
          cs[i][r]=c2; hh[i][r]=h2v; asum[i][r]+=h2v;
        }
        Hs[m*16+lr]=f2b(hh[i][r]);
      }
    __syncthreads();
    #pragma unroll
    for (int q=0;q<2;q++){
      int cc=tid*2+q, sm=cc>>2, pt=cc&3;
      *(u64*)(hn + (size_t)(bt*128+sm)*512 + kc*16 + pt*4) = *(const u64*)(Hs + sm*16 + pt*4);
    }
    arrive(flags, kc, (unsigned)(t+1));
    // shadow: x-part for t+1
    #pragma unroll
    for (int i=0;i<2;i++)
      #pragma unroll
      for (int g=0;g<4;g++) xacc[i][g]=(f32x4){0.f,0.f,0.f,0.f};
    if (t<255) xpart(t+1, xacc);
  }
  #pragma unroll
  for (int i=0;i<2;i++)
    #pragma unroll
    for (int r=0;r<4;r++){
      int m=w*32+i*16+(lane>>4)*4+r;
      P.pooled[(size_t)(bt*128+m)*1024 + (size_t)dir*512 + cg]=f2b(asum[i][r]/(float)elen[i][r]);
    }
}

// ================= persistent decoder (8 groups x 64 samples, 2 hops/step) =================
// grid 256: grp=bx&7, kc=bx>>3. All blocks: G (64 gate rows). kc<16: F1 (16 r1-cols). kc in[16,24): F2+outd.
struct DecP {
  const u16 *Whhd, *Wcmp, *W1d, *W2d;
  const float *gix, *gp0, *pb, *b1d, *b2d;
  u16 *h0,*h1,*r1a,*r1b;
  float* outd;
  unsigned* flags;   // per group: [0..32) G flags, [32..48) F flags (x32 stride)
};

__global__ __launch_bounds__(256,1) void dec_persist(DecP P){
  __shared__ __align__(16) u16 Wh [64*520];
  __shared__ __align__(16) u16 WcL[64*264];
  __shared__ __align__(16) u16 F12[16*520];
  __shared__ __align__(16) u16 Hs[64*16];
  const int tid=threadIdx.x, lane=tid&63, w=tid>>6;
  const int bx=blockIdx.x;
  const int grp=bx&7, kc=bx>>3;
  const int g0 = grp*64;
  const int lr=lane&15, lk=(lane>>4)*8;
  unsigned* flags = P.flags + grp*2048;

  for (int idx=tid; idx<64*64; idx+=256){
    int row=idx>>6, col=(idx&63)*8;
    int g=row>>4, c=row&15;
    size_t grow=(size_t)(g*512+kc*16+c);
    *(s16x8*)(Wh + row*520 + col) = *(const s16x8*)(P.Whhd + grow*512 + col);
  }
  for (int idx=tid; idx<64*32; idx+=256){
    int row=idx>>5, col=(idx&31)*8;
    int g=row>>4, c=row&15;
    size_t grow=(size_t)(g*512+kc*16+c);
    *(s16x8*)(WcL + row*264 + col) = *(const s16x8*)(P.Wcmp + grow*256 + col);
  }
  if (kc<16){
    for (int idx=tid; idx<16*64; idx+=256){
      int rr=idx>>6, col=(idx&63)*8;
      *(s16x8*)(F12 + rr*520 + col) = *(const s16x8*)(P.W1d + (size_t)(kc*16+rr)*512 + col);
    }
  } else if (kc<24){
    for (int idx=tid; idx<16*32; idx+=256){
      int rr=idx>>5, col=(idx&31)*8;
      *(s16x8*)(F12 + rr*264 + col) = *(const s16x8*)(P.W2d + (size_t)((kc-16)*16+rr)*256 + col);
    }
  }
  float gx[4][4]; float pbr[4];
  #pragma unroll
  for (int g=0;g<4;g++)
    #pragma unroll
    for (int r=0;r<4;r++){
      int m=w*16+(lane>>4)*4+r;
      gx[g][r]=P.gix[(size_t)(g0+m)*2048 + (size_t)g*512 + kc*16 + lr];
    }
  #pragma unroll
  for (int g=0;g<4;g++) pbr[g] = P.pb[(size_t)g*512 + kc*16 + lr];
  const float b1=(kc<16)? P.b1d[kc*16+lr] : 0.f;
  const float b2=(kc>=16&&kc<24)? P.b2d[(kc-16)*16+lr] : 0.f;
  const int ar = w*16 + lr;   // this lane's sample row (each wave owns 16 samples)
  float cs[4];
  f32x4 gh[4];
  #pragma unroll
  for (int r=0;r<4;r++) cs[r]=0.f;
  #pragma unroll
  for (int g=0;g<4;g++) gh[g]=(f32x4){0.f,0.f,0.f,0.f};
  __syncthreads();   // weights staged

  for (int t=0;t<256;t++){
    const u16* r1rd = (t&1)? P.r1b : P.r1a;
    u16* hn = (t&1)? P.h0 : P.h1;
    f32x4 acc[4];
    if (t==0){
      #pragma unroll
      for (int g=0;g<4;g++)
        #pragma unroll
        for (int r=0;r<4;r++){
          int m=w*16+(lane>>4)*4+r;
          acc[g][r] = gx[g][r] + P.gp0[(size_t)(g0+m)*2048 + (size_t)g*512 + kc*16 + lr];
        }
    } else {
      waitflags(flags, 32, 16, (unsigned)t);   // r1_t ready
      #pragma unroll
      for (int g=0;g<4;g++){
        f32x4 gv = (f32x4){gx[g][0]+pbr[g], gx[g][1]+pbr[g], gx[g][2]+pbr[g], gx[g][3]+pbr[g]};
        acc[g] = gh[g] + gv;
      }
      // Wcomp . r1_t (K=256), direct per-lane loads
      const u16* rb = r1rd + (size_t)(g0+ar)*256;
      #pragma unroll
      for (int k=0;k<4;k++)
        #pragma unroll
        for (int kk=0;kk<2;kk++){
          bv8 a = ldf(rb + k*64 + kk*32 + lk);
          #pragma unroll
          for (int g=0;g<4;g++){
            bv8 bf=ldf(WcL + (g*16+lr)*264 + k*64 + kk*32 + lk);
            acc[g]=mfma16(a,bf,acc[g]);
          }
        }
    }
    // cell
    #pragma unroll
    for (int r=0;r<4;r++){
      float iv=sigm(acc[0][r]), fv=sigm(acc[1][r]);
      float gv=tanh_(acc[2][r]), ov=sigm(acc[3][r]);
      float c2=fv*cs[r]+iv*gv, h2v=ov*tanh_(c2);
      cs[r]=c2;
      int m=w*16+(lane>>4)*4+r;
      Hs[m*16+lr]=f2b(h2v);
    }
    __syncthreads();
    {
      int sm=tid>>2, pt=tid&3;
      *(u64*)(hn + (size_t)(g0+sm)*512 + kc*16 + pt*4) = *(const u64*)(Hs + sm*16 + pt*4);
    }
    arrive(flags, kc, (unsigned)(t+1));      // G flag
    // shadow: pose_t -> outd[t-1] (F2 blocks; r1_t already acquired this step)
    if (kc>=16 && kc<24 && t>0){
      const u16* rb = r1rd + (size_t)(g0+ar)*256;
      f32x4 fa2=(f32x4){0.f,0.f,0.f,0.f};
      #pragma unroll
      for (int k=0;k<4;k++)
        #pragma unroll
        for (int kk=0;kk<2;kk++){
          bv8 a = ldf(rb + k*64 + kk*32 + lk);
          bv8 bf=ldf(F12 + lr*264 + k*64 + kk*32 + lk);
          fa2=mfma16(a,bf,fa2);
        }
      int pc=(kc-16)*16+lr;
      #pragma unroll
      for (int r=0;r<4;r++){
        int m=w*16+(lane>>4)*4+r;
        __builtin_nontemporal_store(fa2[r]+b2, P.outd + (size_t)(g0+m)*32768 + (size_t)(t-1)*128 + pc);
      }
    }
    waitflags(flags, 0, 32, (unsigned)(t+1));     // h_{t+1} ready
    // F: gh' = Whh.h_{t+1} (K=512) + fused F1 (kc<16)
    f32x4 gn[4]; f32x4 fa=(f32x4){0.f,0.f,0.f,0.f};
    #pragma unroll
    for (int g=0;g<4;g++) gn[g]=(f32x4){0.f,0.f,0.f,0.f};
    {
      const u16* hb = hn + (size_t)(g0+ar)*512;
      #pragma unroll
      for (int k=0;k<8;k++)
        #pragma unroll
        for (int kk=0;kk<2;kk++){
          bv8 a = ldf(hb + k*64 + kk*32 + lk);
          #pragma unroll
          for (int g=0;g<4;g++){
            bv8 bf=ldf(Wh + (g*16+lr)*520 + k*64 + kk*32 + lk);
            gn[g]=mfma16(a,bf,gn[g]);
          }
          if (kc<16){
            bv8 bf=ldf(F12 + lr*520 + k*64 + kk*32 + lk);
            fa=mfma16(a,bf,fa);
          }
        }
    }
    #pragma unroll
    for (int g=0;g<4;g++) gh[g]=gn[g];
    if (kc<16){
      u16* r1w = (t&1)? P.r1a : P.r1b;     // parity (t+1)&1
      #pragma unroll
      for (int r=0;r<4;r++){
        int m=w*16+(lane>>4)*4+r;
        Hs[m*16+lr]=f2b(fmaxf(fa[r]+b1,0.f));
      }
      __syncthreads();
      {
        int sm=tid>>2, pt=tid&3;
        *(u64*)(r1w + (size_t)(g0+sm)*256 + kc*16 + pt*4) = *(const u64*)(Hs + sm*16 + pt*4);
      }
      arrive(flags, 32+kc, (unsigned)(t+1));   // F flag
    }
  }
  // epilogue: pose_256 -> outd[255]
  if (kc>=16 && kc<24){
    waitflags(flags, 32, 16, 256u);
    const u16* rb = P.r1a + (size_t)(g0+ar)*256;  // r1_256 parity 0
    f32x4 fa2=(f32x4){0.f,0.f,0.f,0.f};
    #pragma unroll
    for (int k=0;k<4;k++)
      #pragma unroll
      for (int kk=0;kk<2;kk++){
        bv8 a = ldf(rb + k*64 + kk*32 + lk);
        bv8 bf=ldf(F12 + lr*264 + k*64 + kk*32 + lk);
        fa2=mfma16(a,bf,fa2);
      }
    int pc=(kc-16)*16+lr;
    #pragma unroll
    for (int r=0;r<4;r++){
      int m=w*16+(lane>>4)*4+r;
      __builtin_nontemporal_store(fa2[r]+b2, P.outd + (size_t)(g0+m)*32768 + (size_t)255*128 + pc);
    }
  }
}

__global__ __launch_bounds__(512) void len_cast(const int* __restrict__ lens, float* __restrict__ out){
  int i = threadIdx.x;
  if (i < 512) out[i] = (float)lens[i];
}

// ============================== host ==============================
extern "C" void kernel_launch(void* const* d_in, const int* in_sizes, int n_in,
                              void* d_out, int out_size, void* d_ws, size_t ws_size,
                              hipStream_t stream){
  (void)in_sizes; (void)n_in; (void)out_size; (void)ws_size;
  const float* x      = (const float*)d_in[0];
  const int*   lens   = (const int*)d_in[1];
  const float* ng     = (const float*)d_in[2];
  const float* nb     = (const float*)d_in[3];
  const float* We     = (const float*)d_in[4];
  const float* be     = (const float*)d_in[5];
  const float* Wih_f  = (const float*)d_in[6];
  const float* Whh_f  = (const float*)d_in[7];
  const float* bih_f  = (const float*)d_in[8];
  const float* bhh_f  = (const float*)d_in[9];
  const float* Wih_b  = (const float*)d_in[10];
  const float* Whh_b  = (const float*)d_in[11];
  const float* bih_b  = (const float*)d_in[12];
  const float* bhh_b  = (const float*)d_in[13];
  const float* W1e    = (const float*)d_in[14];
  const float* b1e    = (const float*)d_in[15];
  const float* W2e    = (const float*)d_in[16];
  const float* b2e    = (const float*)d_in[17];
  const float* Wd     = (const float*)d_in[18];
  const float* bd     = (const float*)d_in[19];
  const float* Wp1    = (const float*)d_in[20];
  const float* bp1    = (const float*)d_in[21];
  const float* Wp2    = (const float*)d_in[22];
  const float* bp2    = (const float*)d_in[23];
  const float* Wih_d  = (const float*)d_in[24];
  const float* Whh_d  = (const float*)d_in[25];
  const float* bih_d  = (const float*)d_in[26];
  const float* bhh_d  = (const float*)d_in[27];
  const float* W1d    = (const float*)d_in[28];
  const float* b1d    = (const float*)d_in[29];
  const float* W2d    = (const float*)d_in[30];
  const float* b2d    = (const float*)d_in[31];

  char* p = (char*)d_ws;
  auto carve = [&](size_t bytes)->void*{ void* r=(void*)p; p += (bytes+255)&~(size_t)255; return r; };
  float* mu   = (float*)carve(512*4);
  float* rstd = (float*)carve(512*4);
  u16* xe     = (u16*)carve((size_t)33554432*2);
  u16* wWe  = (u16*)carve(32768*2);
  u16* wIhf = (u16*)carve(524288*2);
  u16* wHhf = (u16*)carve(1048576*2);
  u16* wIhb = (u16*)carve(524288*2);
  u16* wHhb = (u16*)carve(1048576*2);
  u16* wW1e = (u16*)carve(524288*2);
  u16* wW2e = (u16*)carve(131072*2);
  u16* wWd  = (u16*)carve(65536*2);
  u16* wWp1 = (u16*)carve(65536*2);
  u16* wWp2 = (u16*)carve(32768*2);
  u16* wIhd = (u16*)carve(786432*2);
  u16* wHhd = (u16*)carve(1048576*2);
  u16* wW1d = (u16*)carve(131072*2);
  u16* wW2d = (u16*)carve(32768*2);
  u16* wW2dT  = (u16*)carve(32768*2);
  u16* wWcomp = (u16*)carve(524288*2);
  float* pbv  = (float*)carve(2048*4);
  float* gp0f = (float*)carve((size_t)1048576*4);
  u16* hf0  = (u16*)carve(524288);
  u16* hf1  = (u16*)carve(524288);
  u16* hb0  = (u16*)carve(524288);
  u16* hb1  = (u16*)carve(524288);
  u16* hd0  = (u16*)carve(524288);
  u16* hd1  = (u16*)carve(524288);
  u16* r1a  = (u16*)carve(262144);
  u16* r1b  = (u16*)carve(262144);
  u16* pooled = (u16*)carve(1048576);
  u16* out1   = (u16*)carve(524288);
  u16* zlat   = (u16*)carve(262144);
  u16* x0     = (u16*)carve(262144);
  u16* t0     = (u16*)carve(262144);
  float* gix  = (float*)carve(4194304);
  u16* pose   = (u16*)carve(131072);
  unsigned* barflags = (unsigned*)carve(16*2048*4);

  float* out_x   = (float*)d_out;
  float* out_dec = out_x + 16777216;
  float* out_len = out_x + 33554432;

  hipMemcpyAsync(out_x, x, (size_t)16777216*4, hipMemcpyDeviceToDevice, stream);
  hipMemsetAsync(hf0,0,524288,stream);
  hipMemsetAsync(hb0,0,524288,stream);
  hipMemsetAsync(barflags,0,16*2048*4,stream);

  CvtJobs J;
  const float* srcs[14] = {We,Wih_f,Whh_f,Wih_b,Whh_b,W1e,W2e,Wd,Wp1,Wp2,Wih_d,Whh_d,W1d,W2d};
  u16* dsts[14] = {wWe,wIhf,wHhf,wIhb,wHhb,wW1e,wW2e,wWd,wWp1,wWp2,wIhd,wHhd,wW1d,wW2d};
  int ns[14] = {32768,524288,1048576,524288,1048576,524288,131072,65536,65536,32768,786432,1048576,131072,32768};
  int blk=0;
  for (int i=0;i<14;i++){ J.s[i]=srcs[i]; J.d[i]=dsts[i]; J.start[i]=blk; blk += ns[i]/2048; }
  cvt_w<<<blk,256,0,stream>>>(J);

  tr_w2d<<<128,256,0,stream>>>(wW2d, wW2dT);
  pb_k<<<8,256,0,stream>>>(Wih_d, b2d, pbv);
  gemm_bt<64,64,false,false><<<dim3(4,32),256,0,stream>>>(wIhd+256,384, wW2dT,128, nullptr,nullptr, wWcomp,nullptr,256,128);

  ln_stats<<<512,256,0,stream>>>(x,mu,rstd);
  ln_gemm<<<dim3(2,1024),256,0,stream>>>(x,mu,rstd,ng,nb,wWe,be,xe);

  EncP EP = {xe,lens,wIhf,wHhf,wIhb,wHhb,bih_f,bhh_f,bih_b,bhh_b,hf0,hf1,hb0,hb1,pooled,barflags};
  {
    void* ea[] = {&EP};
    if (hipLaunchCooperativeKernel((void*)enc_persist, dim3(256), dim3(256), ea, 0, stream) != hipSuccess)
      enc_persist<<<256,256,0,stream>>>(EP);
  }

  gemm_bt<64,64,true ,false><<<dim3(8,8),256,0,stream>>>(pooled,1024,wW1e,1024,b1e,nullptr,out1,nullptr,512,1024);
  gemm_bt<64,64,false,false><<<dim3(4,8),256,0,stream>>>(out1,512,wW2e,512,b2e,nullptr,zlat,nullptr,256,512);
  gemm_bt<64,64,true ,false><<<dim3(4,8),256,0,stream>>>(zlat,256,wWd,256,bd,nullptr,x0,nullptr,256,256);
  gemm_bt<64,64,true ,false><<<dim3(4,8),256,0,stream>>>(x0,256,wWp1,256,bp1,nullptr,t0,nullptr,256,256);
  gemm_bt<64,64,false,false><<<dim3(2,8),256,0,stream>>>(t0,256,wWp2,256,bp2,nullptr,pose,nullptr,128,256);
  gemm_bt<64,128,false,true><<<dim3(16,8),256,0,stream>>>(x0,256,wIhd,384,bih_d,bhh_d,nullptr,gix,2048,256);
  gemm_bt<64,128,false,true><<<dim3(16,8),256,0,stream>>>(pose,128,wIhd+256,384,nullptr,nullptr,nullptr,gp0f,2048,128);

  DecP DP = {wHhd,wWcomp,wW1d,wW2d, gix,gp0f,pbv,b1d,b2d, hd0,hd1,r1a,r1b, out_dec, barflags + 8*2048};
  {
    void* da[] = {&DP};
    if (hipLaunchCooperativeKernel((void*)dec_persist, dim3(256), dim3(256), da, 0, stream) != hipSuccess)
      dec_persist<<<256,256,0,stream>>>(DP);
  }

  len_cast<<<1,512,0,stream>>>(lens,out_len);
}